// Round 5
// baseline (392.475 us; speedup 1.0000x reference)
//
#include <hip/hip_runtime.h>
#include <hip/hip_bf16.h>

typedef unsigned short u16;
typedef __attribute__((ext_vector_type(8))) short bfrag8;
typedef __attribute__((ext_vector_type(8))) unsigned short u16x8;
typedef __attribute__((ext_vector_type(4))) unsigned short u16x4;
typedef __attribute__((ext_vector_type(4))) float f32x4;

__device__ __forceinline__ float bf2f(u16 u) {
    union { unsigned int i; float f; } v; v.i = ((unsigned int)u) << 16; return v.f;
}
// Hardware cvt: scalar cast lowers to v_cvt_pk_bf16_f32 on gfx950 (RNE, same as
// the old bit-twiddle). Old software version was ~4 VALU ops/element and made
// GEMM1 staging VALU-bound (R3: VALUBusy 42%, MfmaUtil 10%).
__device__ __forceinline__ u16 f2bf(float f) {
    union { __hip_bfloat16 h; u16 u; } cv;
    cv.h = __float2bfloat16(f);
    return cv.u;
}
__device__ __forceinline__ float fast_tanh(float x) {
    float e = __expf(2.f * x);
    return (e - 1.f) / (e + 1.f);
}

#define TILE_M 128
#define TILE_N 128
#define TILE_K 32

// C(M,N) = A(M,K) @ Wt(N,K)^T (+bias). Double-buffered LDS, reg-staged prefetch
// (T14 issue-early/write-late). XCD-chunk swizzle (m204 bijective).
// C_MODE: 0 = bf16 store, 1 = f32 store, 2 = f32 atomicAdd (split-K; exactly 2
// commutative adds onto memset-0 -> bitwise deterministic).
template<int A_F32, int HAS_BIAS, int C_MODE, int NGUARD>
__global__ __launch_bounds__(256)
void gemm_k(const void* __restrict__ Ap, const u16* __restrict__ Bt,
            const float* __restrict__ bias, void* __restrict__ Cp,
            int M, int N, int K, int lda, int ldc, int nt, int kchunk)
{
    __shared__ u16 As[2][TILE_M][TILE_K + 8];
    __shared__ u16 Bs[2][TILE_N][TILE_K + 8];

    const int nwg = gridDim.x;
    const int q = nwg >> 3, r = nwg & 7;
    const int xcd = blockIdx.x & 7, pos = blockIdx.x >> 3;
    const int wg = (xcd < r ? xcd * (q + 1) : r * (q + 1) + (xcd - r) * q) + pos;
    const int m0 = (wg / nt) * TILE_M;
    const int n0 = (wg % nt) * TILE_N;

    const int kc   = blockIdx.y;
    const int kbeg = kc * kchunk;
    const int kend = (kbeg + kchunk < K) ? kbeg + kchunk : K;

    const int t    = threadIdx.x;
    const int lane = t & 63;
    const int w    = t >> 6;
    const int wm   = (w >> 1) * 64;
    const int wn   = (w & 1) * 64;
    const int lr   = lane & 15;
    const int kg   = (lane >> 4) * 8;

    const int srow = t >> 2;         // 0..63
    const int skc  = (t & 3) * 8;    // 0,8,16,24

    // staging registers (tile t+1 in flight)
    float4 pa0, pa1, pa2, pa3;       // A f32 path
    u16x8  qa0, qa1;                 // A bf16 path
    u16x8  qb0, qb1;                 // B

    auto load_tile = [&](int k0) {
        if (A_F32) {
            const float* ap0 = (const float*)Ap + (size_t)(m0 + srow) * lda + k0 + skc;
            const float* ap1 = (const float*)Ap + (size_t)(m0 + srow + 64) * lda + k0 + skc;
            pa0 = *(const float4*)ap0; pa1 = *(const float4*)(ap0 + 4);
            pa2 = *(const float4*)ap1; pa3 = *(const float4*)(ap1 + 4);
        } else {
            const u16* ap0 = (const u16*)Ap + (size_t)(m0 + srow) * lda + k0 + skc;
            const u16* ap1 = (const u16*)Ap + (size_t)(m0 + srow + 64) * lda + k0 + skc;
            qa0 = *(const u16x8*)ap0;
            qa1 = *(const u16x8*)ap1;
        }
        u16x8 z = (u16x8){0,0,0,0,0,0,0,0};
        if (!NGUARD || n0 + srow < N)
            qb0 = *(const u16x8*)(Bt + (size_t)(n0 + srow) * K + k0 + skc);
        else qb0 = z;
        if (!NGUARD || n0 + srow + 64 < N)
            qb1 = *(const u16x8*)(Bt + (size_t)(n0 + srow + 64) * K + k0 + skc);
        else qb1 = z;
    };
    auto store_tile = [&](int buf) {
        if (A_F32) {
            u16x8 v0, v1;
            v0[0] = f2bf(pa0.x); v0[1] = f2bf(pa0.y); v0[2] = f2bf(pa0.z); v0[3] = f2bf(pa0.w);
            v0[4] = f2bf(pa1.x); v0[5] = f2bf(pa1.y); v0[6] = f2bf(pa1.z); v0[7] = f2bf(pa1.w);
            v1[0] = f2bf(pa2.x); v1[1] = f2bf(pa2.y); v1[2] = f2bf(pa2.z); v1[3] = f2bf(pa2.w);
            v1[4] = f2bf(pa3.x); v1[5] = f2bf(pa3.y); v1[6] = f2bf(pa3.z); v1[7] = f2bf(pa3.w);
            *(u16x8*)&As[buf][srow][skc]      = v0;
            *(u16x8*)&As[buf][srow + 64][skc] = v1;
        } else {
            *(u16x8*)&As[buf][srow][skc]      = qa0;
            *(u16x8*)&As[buf][srow + 64][skc] = qa1;
        }
        *(u16x8*)&Bs[buf][srow][skc]      = qb0;
        *(u16x8*)&Bs[buf][srow + 64][skc] = qb1;
    };

    f32x4 acc[4][4];
#pragma unroll
    for (int i = 0; i < 4; ++i)
#pragma unroll
        for (int j = 0; j < 4; ++j) acc[i][j] = (f32x4){0.f, 0.f, 0.f, 0.f};

    load_tile(kbeg);
    store_tile(0);
    __syncthreads();
    int cur = 0;

    for (int k0 = kbeg; k0 < kend; k0 += TILE_K) {
        const bool more = (k0 + TILE_K) < kend;
        if (more) load_tile(k0 + TILE_K);          // in flight during MFMA phase

        bfrag8 af[4], bfr[4];
#pragma unroll
        for (int mi = 0; mi < 4; ++mi) af[mi]  = *(const bfrag8*)&As[cur][wm + mi * 16 + lr][kg];
#pragma unroll
        for (int ni = 0; ni < 4; ++ni) bfr[ni] = *(const bfrag8*)&Bs[cur][wn + ni * 16 + lr][kg];
#pragma unroll
        for (int mi = 0; mi < 4; ++mi)
#pragma unroll
            for (int ni = 0; ni < 4; ++ni)
                acc[mi][ni] = __builtin_amdgcn_mfma_f32_16x16x32_bf16(af[mi], bfr[ni], acc[mi][ni], 0, 0, 0);

        if (more) {
            store_tile(cur ^ 1);                   // vmcnt wait lands here, not at load
            __syncthreads();
            cur ^= 1;
        }
    }

#pragma unroll
    for (int mi = 0; mi < 4; ++mi) {
#pragma unroll
        for (int ni = 0; ni < 4; ++ni) {
            int col = n0 + wn + ni * 16 + lr;
            if (!NGUARD || col < N) {
                int row = m0 + wm + mi * 16 + (lane >> 4) * 4;
                float bv = 0.f;
                if (HAS_BIAS && (C_MODE != 2 || kc == 0)) bv = bias[col];
#pragma unroll
                for (int rr = 0; rr < 4; ++rr) {
                    float v = acc[mi][ni][rr] + bv;
                    if (C_MODE == 0)      ((u16*)Cp)[(size_t)(row + rr) * ldc + col] = f2bf(v);
                    else if (C_MODE == 1) ((float*)Cp)[(size_t)(row + rr) * ldc + col] = v;
                    else                  atomicAdd((float*)Cp + (size_t)(row + rr) * ldc + col, v);
                }
            }
        }
    }
}

// scores[row][8] = [s_src h0..3, s_dst h0..3]; one wave per row of h (bf16).
__global__ __launch_bounds__(256)
void score_k(const u16* __restrict__ hs, int ld,
             const float* __restrict__ a_src, const float* __restrict__ a_dst,
             float* __restrict__ scores, int Mrows)
{
    const int wid  = blockIdx.x * 4 + (threadIdx.x >> 6);
    const int lane = threadIdx.x & 63;
    if (wid >= Mrows) return;
    const u16* hp = hs + (size_t)wid * ld + lane * 4;
    u16x4 xv = *(const u16x4*)hp;
    float s1 = 0.f, s2 = 0.f;
#pragma unroll
    for (int k = 0; k < 4; ++k) {
        float x = bf2f(xv[k]);
        s1 = fmaf(x, a_src[lane * 4 + k], s1);
        s2 = fmaf(x, a_dst[lane * 4 + k], s2);
    }
#pragma unroll
    for (int off = 1; off < 16; off <<= 1) {
        s1 += __shfl_xor(s1, off);
        s2 += __shfl_xor(s2, off);
    }
    if ((lane & 15) == 0) {
        scores[(size_t)wid * 8 + (lane >> 4)] = s1;
        scores[(size_t)wid * 8 + 4 + (lane >> 4)] = s2;
    }
}

// One thread per (b,h): full 7x7 leaky-relu + mask + top-3 + softmax.
template<int WRITE_ATTN>
__global__ __launch_bounds__(256)
void alpha_k(const float* __restrict__ scores, const float* __restrict__ em2,
             float* __restrict__ alpha, float* __restrict__ attn_out)
{
    const int t = blockIdx.x * 256 + threadIdx.x;
    const int b = t >> 2;
    const int h = t & 3;

    float ssrc[7], sdst[7];
#pragma unroll
    for (int n = 0; n < 7; ++n) {
        ssrc[n] = scores[(size_t)(b * 7 + n) * 8 + h];
        sdst[n] = scores[(size_t)(b * 7 + n) * 8 + 4 + h];
    }

    float al[49];
#pragma unroll
    for (int i = 0; i < 7; ++i) {
        float e[7];
#pragma unroll
        for (int j = 0; j < 7; ++j) {
            float v = ssrc[i] + sdst[j];
            v = fmaxf(v, 0.2f * v);
            e[j] = fmaf(v, em2[(i * 7 + j) * 2], em2[(i * 7 + j) * 2 + 1]);
        }
        float a1 = -3e38f, b1 = -3e38f, c1 = -3e38f;
#pragma unroll
        for (int j = 0; j < 7; ++j) {
            float v = e[j];
            float t2 = fminf(a1, v); a1 = fmaxf(a1, v);
            float t3 = fminf(b1, t2); b1 = fmaxf(b1, t2);
            c1 = fmaxf(c1, t3);
        }
        float psum = 0.f;
        float p[7];
#pragma unroll
        for (int j = 0; j < 7; ++j) {
            float qv = (e[j] >= c1) ? __expf(e[j] - a1) : 0.f;
            p[j] = qv; psum += qv;
        }
        float inv = 1.f / psum;
#pragma unroll
        for (int j = 0; j < 7; ++j) al[i * 7 + j] = p[j] * inv;
    }

    float* ap = alpha + (size_t)t * 49;
#pragma unroll
    for (int j = 0; j < 49; ++j) ap[j] = al[j];

    if (WRITE_ATTN) {
#pragma unroll
        for (int j = 0; j < 49; ++j) {
            float m = al[j];
            m += __shfl_xor(m, 1);
            m += __shfl_xor(m, 2);
            if (h == 0) attn_out[(size_t)b * 49 + j] = 0.25f * m;
        }
    }
}

// PV + residual + LN + relu. block=256: wave=head h, lane=d.
__global__ __launch_bounds__(256)
void gat_apply_k(const u16* __restrict__ hh, int ld_hh,
                 const u16* __restrict__ resid, int ld_res, int res_off,
                 const float* __restrict__ alpha,
                 const float* __restrict__ ln_w, const float* __restrict__ ln_b,
                 u16* __restrict__ outp, int out_bs)
{
    const int b = blockIdx.x;
    const int t = threadIdx.x;
    const int h = __builtin_amdgcn_readfirstlane(t >> 6);
    const int d = t & 63;
    const int c = (h << 6) + d;
    const size_t rowbase = (size_t)b * 7;

    float al[49];
    const float* ap = alpha + ((size_t)b * 4 + h) * 49;
#pragma unroll
    for (int j = 0; j < 49; ++j) al[j] = ap[j];

    float hv[7];
#pragma unroll
    for (int n = 0; n < 7; ++n) hv[n] = bf2f(hh[(rowbase + n) * ld_hh + c]);

    __shared__ float s_red[7][4][2];

    float xv[7];
#pragma unroll
    for (int i = 0; i < 7; ++i) {
        float pv = 0.f;
#pragma unroll
        for (int j = 0; j < 7; ++j) pv = fmaf(al[i * 7 + j], hv[j], pv);
        float x = pv + bf2f(resid[(rowbase + i) * ld_res + res_off + c]);
        xv[i] = x;
        float s1 = x, s2 = x * x;
#pragma unroll
        for (int off = 32; off > 0; off >>= 1) {
            s1 += __shfl_xor(s1, off);
            s2 += __shfl_xor(s2, off);
        }
        if (d == 0) { s_red[i][h][0] = s1; s_red[i][h][1] = s2; }
    }
    __syncthreads();
#pragma unroll
    for (int i = 0; i < 7; ++i) {
        float s1 = s_red[i][0][0] + s_red[i][1][0] + s_red[i][2][0] + s_red[i][3][0];
        float s2 = s_red[i][0][1] + s_red[i][1][1] + s_red[i][2][1] + s_red[i][3][1];
        float mu  = s1 * (1.f / 256.f);
        float var = fmaxf(s2 * (1.f / 256.f) - mu * mu, 0.f);
        float inv = rsqrtf(var + 1e-5f);
        float y = (xv[i] - mu) * inv * ln_w[c] + ln_b[c];
        y = fmaxf(y, 0.f);
        outp[(size_t)b * out_bs + i * 256 + c] = f2bf(y);
    }
}

// weight transpose/cast + bias fuse + edge_mask
__global__ __launch_bounds__(256)
void prep_k(const float* __restrict__ W1, const float* __restrict__ skip_w, const float* __restrict__ W2,
            const float* __restrict__ base_w1, const float* __restrict__ reg_w1, const float* __restrict__ res_w1,
            const float* __restrict__ skip_b, const float* __restrict__ base_b1, const float* __restrict__ reg_b1,
            const float* __restrict__ res_b1, const float* __restrict__ edge_logits,
            u16* __restrict__ Wt1, u16* __restrict__ Wt2, u16* __restrict__ Wt3,
            float* __restrict__ bias1, float* __restrict__ bias3,
            float* __restrict__ em2, float* __restrict__ em_out)
{
    int idx = blockIdx.x * 256 + threadIdx.x;
    if (idx < 512 * 256) {            // Wt1[n][k] = [W1|skip_w][k][n]
        int n = idx >> 8, k = idx & 255;
        float v = (n < 256) ? W1[k * 256 + n] : skip_w[k * 256 + (n - 256)];
        Wt1[n * 256 + k] = f2bf(v); return;
    }
    idx -= 512 * 256;
    if (idx < 256 * 256) {
        int n = idx >> 8, k = idx & 255;
        Wt2[n * 256 + k] = f2bf(W2[k * 256 + n]); return;
    }
    idx -= 256 * 256;
    if (idx < 80 * 1920) {            // Wt3[n][k] = [base_w1|reg_w1|res_w1][k][n]
        int n = idx / 1920, k = idx % 1920;
        float v = (n < 32) ? base_w1[k * 32 + n] : (n < 64) ? reg_w1[k * 32 + (n - 32)] : res_w1[k * 16 + (n - 64)];
        Wt3[n * 1920 + k] = f2bf(v); return;
    }
    idx -= 80 * 1920;
    if (idx < 512) { bias1[idx] = (idx < 256) ? 0.f : skip_b[idx - 256]; return; }
    idx -= 512;
    if (idx < 80) {
        bias3[idx] = (idx < 32) ? base_b1[idx] : (idx < 64) ? reg_b1[idx - 32] : res_b1[idx - 64];
        return;
    }
    idx -= 80;
    if (idx < 49) {
        int i = idx / 7, j = idx % 7;
        float s = 1.f / (1.f + __expf(-edge_logits[idx]));
        float m = (i == j) ? 1.f : s;
        em2[idx * 2] = m;
        em2[idx * 2 + 1] = (1.f - m) * (-1e9f);
        em_out[idx] = m;
    }
}

__global__ __launch_bounds__(256)
void ctx_k(const float* __restrict__ ctx, u16* __restrict__ comb)
{
    int idx = blockIdx.x * 256 + threadIdx.x;   // B*128
    int b = idx >> 7, cc = idx & 127;
    comb[(size_t)b * 1920 + 1792 + cc] = f2bf(ctx[idx]);
}

__global__ __launch_bounds__(256)
void head_finish(const float* __restrict__ ho, const float* __restrict__ bp, const float* __restrict__ rf,
                 const float* __restrict__ bw2, const float* __restrict__ bb2,
                 const float* __restrict__ rw2, const float* __restrict__ rb2,
                 const float* __restrict__ gw1, const float* __restrict__ gb1,
                 const float* __restrict__ gw2, const float* __restrict__ gb2,
                 const float* __restrict__ resw2, const float* __restrict__ resb2,
                 float* __restrict__ out_pred, float* __restrict__ out_w, float* __restrict__ out_gate, int B)
{
    int b = blockIdx.x * 256 + threadIdx.x;
    if (b >= B) return;
    const float* o = ho + (size_t)b * 80;

    float z0 = bb2[0], z1 = bb2[1];
#pragma unroll 8
    for (int k = 0; k < 32; ++k) { float v = fmaxf(o[k], 0.f); z0 += v * bw2[k * 2]; z1 += v * bw2[k * 2 + 1]; }
    float mz = fmaxf(z0, z1); float e0 = __expf(z0 - mz), e1 = __expf(z1 - mz); float inv = 1.f / (e0 + e1);
    float wb0 = e0 * inv, wb1 = e1 * inv;

    z0 = rb2[0]; z1 = rb2[1];
#pragma unroll 8
    for (int k = 0; k < 32; ++k) { float v = fmaxf(o[32 + k], 0.f); z0 += v * rw2[k * 2]; z1 += v * rw2[k * 2 + 1]; }
    mz = fmaxf(z0, z1); e0 = __expf(z0 - mz); e1 = __expf(z1 - mz); inv = 1.f / (e0 + e1);
    float wr0 = e0 * inv, wr1 = e1 * inv;

    float g = gb2[0];
#pragma unroll
    for (int j = 0; j < 8; ++j) {
        float a = gb1[j];
#pragma unroll
        for (int i = 0; i < 3; ++i) a += rf[(size_t)b * 3 + i] * gw1[i * 8 + j];
        g += fast_tanh(a) * gw2[j];
    }
    float gg = 1.f / (1.f + __expf(-g));
    float w0 = (1.f - gg) * wb0 + gg * wr0;
    float w1 = (1.f - gg) * wb1 + gg * wr1;
    float pred = w0 * bp[(size_t)b * 2] + w1 * bp[(size_t)b * 2 + 1];
    float r = resb2[0];
#pragma unroll 8
    for (int k = 0; k < 16; ++k) r += fast_tanh(o[64 + k]) * resw2[k];
    pred = fmaxf(pred + r * 0.05f, 0.05f);
    out_pred[b] = pred;
    out_w[(size_t)b * 2] = w0; out_w[(size_t)b * 2 + 1] = w1;
    out_gate[b] = gg;
}

extern "C" void kernel_launch(void* const* d_in, const int* in_sizes, int n_in,
                              void* d_out, int out_size, void* d_ws, size_t ws_size,
                              hipStream_t stream)
{
    const int B = in_sizes[1] / 128;     // context is (B,128)
    const int Mbig = B * 7;

    const float* node_feats   = (const float*)d_in[0];
    const float* context      = (const float*)d_in[1];
    const float* base_preds   = (const float*)d_in[2];
    const float* regime_feats = (const float*)d_in[3];
    const float* edge_logits  = (const float*)d_in[4];
    const float* W1      = (const float*)d_in[5];
    const float* a_src1  = (const float*)d_in[6];
    const float* a_dst1  = (const float*)d_in[7];
    const float* W2      = (const float*)d_in[8];
    const float* a_src2  = (const float*)d_in[9];
    const float* a_dst2  = (const float*)d_in[10];
    const float* ln1_w   = (const float*)d_in[11];
    const float* ln1_b   = (const float*)d_in[12];
    const float* ln2_w   = (const float*)d_in[13];
    const float* ln2_b   = (const float*)d_in[14];
    const float* skip_w  = (const float*)d_in[15];
    const float* skip_b  = (const float*)d_in[16];
    const float* base_w1 = (const float*)d_in[17];
    const float* base_b1 = (const float*)d_in[18];
    const float* base_w2 = (const float*)d_in[19];
    const float* base_b2 = (const float*)d_in[20];
    const float* reg_w1  = (const float*)d_in[21];
    const float* reg_b1  = (const float*)d_in[22];
    const float* reg_w2  = (const float*)d_in[23];
    const float* reg_b2  = (const float*)d_in[24];
    const float* gate_w1 = (const float*)d_in[25];
    const float* gate_b1 = (const float*)d_in[26];
    const float* gate_w2 = (const float*)d_in[27];
    const float* gate_b2 = (const float*)d_in[28];
    const float* res_w1  = (const float*)d_in[29];
    const float* res_b1  = (const float*)d_in[30];
    const float* res_w2  = (const float*)d_in[31];
    const float* res_b2  = (const float*)d_in[32];

    // workspace layout (bytes)
    char* ws = (char*)d_ws;
    size_t off = 0;
    u16* hs1 = (u16*)(ws + off);                       // [h1_pre|skip] Mbig x 512 bf16
    u16* hh2 = (u16*)(ws + off);                       // reuse after GAT1: Mbig x 256 bf16
    off += (size_t)Mbig * 512 * 2;
    u16* hbuf = (u16*)(ws + off);  off += (size_t)Mbig * 256 * 2;   // h: Mbig x 256 bf16
    u16* comb = (u16*)(ws + off);  off += (size_t)B * 1920 * 2;     // combined: B x 1920 bf16
    float* headout = (float*)(ws + off); off += (size_t)B * 80 * 4; // B x 80 f32
    u16* Wt1 = (u16*)(ws + off); off += 512 * 256 * 2;
    u16* Wt2 = (u16*)(ws + off); off += 256 * 256 * 2;
    u16* Wt3 = (u16*)(ws + off); off += (size_t)80 * 1920 * 2;
    float* bias1 = (float*)(ws + off); off += 512 * 4;
    float* bias3 = (float*)(ws + off); off += 128 * 4;
    float* em2   = (float*)(ws + off); off += 128 * 4;
    float* scoresb = (float*)(ws + off); off += (size_t)Mbig * 8 * 4;   // row scores f32
    float* alphab  = (float*)(ws + off); off += (size_t)B * 4 * 49 * 4; // alpha f32

    float* out_pred = (float*)d_out;
    float* out_w    = out_pred + B;
    float* out_gate = out_pred + 3 * (size_t)B;
    float* out_em   = out_pred + 4 * (size_t)B;
    float* out_attn = out_pred + 4 * (size_t)B + 49;

    const int B4blocks = (B * 4) / 256;

    // 1. weight prep + edge mask
    prep_k<<<dim3(1371), dim3(256), 0, stream>>>(W1, skip_w, W2, base_w1, reg_w1, res_w1,
        skip_b, base_b1, reg_b1, res_b1, edge_logits, Wt1, Wt2, Wt3, bias1, bias3, em2, out_em);

    // 2. GEMM1: node_feats(f32) @ [W1|skip_w] -> hs1 (bf16), bias=[0|skip_b]
    gemm_k<1, 1, 0, 0><<<dim3((Mbig / 128) * 4, 1), dim3(256), 0, stream>>>(
        (const void*)node_feats, Wt1, bias1, (void*)hs1, Mbig, 512, 256, 256, 512, 4, 256);

    // 3. scores from h1 (= hs1 cols 0..255)
    score_k<<<dim3(Mbig / 4), dim3(256), 0, stream>>>(hs1, 512, a_src1, a_dst1, scoresb, Mbig);

    // 4. alpha for GAT1
    alpha_k<0><<<dim3(B4blocks), dim3(256), 0, stream>>>(scoresb, em2, alphab, (float*)nullptr);

    // 5. GAT1 apply: PV + skip-resid + LN1 + relu -> hbuf
    gat_apply_k<<<dim3(B), dim3(256), 0, stream>>>(
        hs1, 512, hs1, 512, 256, alphab, ln1_w, ln1_b, hbuf, 1792);

    // 6. GEMM2: h @ W2 -> hh2 (reuses hs1 region)
    gemm_k<0, 0, 0, 0><<<dim3((Mbig / 128) * 2, 1), dim3(256), 0, stream>>>(
        (const void*)hbuf, Wt2, (const float*)nullptr, (void*)hh2, Mbig, 256, 256, 256, 256, 2, 256);

    // 7. scores from h2
    score_k<<<dim3(Mbig / 4), dim3(256), 0, stream>>>(hh2, 256, a_src2, a_dst2, scoresb, Mbig);

    // 8. alpha for GAT2 (+ attn mean output)
    alpha_k<1><<<dim3(B4blocks), dim3(256), 0, stream>>>(scoresb, em2, alphab, out_attn);

    // 9. GAT2 apply: PV + h-resid + LN2 + relu -> comb[:, :1792]
    gat_apply_k<<<dim3(B), dim3(256), 0, stream>>>(
        hh2, 256, hbuf, 256, 0, alphab, ln2_w, ln2_b, comb, 1920);

    // 10. context -> comb[:, 1792:]
    ctx_k<<<dim3(B * 128 / 256), dim3(256), 0, stream>>>(context, comb);

    // 11. GEMM3: comb @ [base_w1|reg_w1|res_w1] + bias -> headout (f32), split-K x2
    hipMemsetAsync(headout, 0, (size_t)B * 80 * 4, stream);
    gemm_k<0, 1, 2, 1><<<dim3(B / 128, 2), dim3(256), 0, stream>>>(
        (const void*)comb, Wt3, bias3, (void*)headout, B, 80, 1920, 1920, 80, 1, 960);

    // 12. heads -> pred, weights, gate
    head_finish<<<dim3((B + 255) / 256), dim3(256), 0, stream>>>(
        headout, base_preds, regime_feats, base_w2, base_b2, reg_w2, reg_b2,
        gate_w1, gate_b1, gate_w2, gate_b2, res_w2, res_b2, out_pred, out_w, out_gate, B);
}

// Round 6
// 390.390 us; speedup vs baseline: 1.0053x; 1.0053x over previous
//
#include <hip/hip_runtime.h>
#include <hip/hip_bf16.h>

typedef unsigned short u16;
typedef __attribute__((ext_vector_type(8))) short bfrag8;
typedef __attribute__((ext_vector_type(8))) unsigned short u16x8;
typedef __attribute__((ext_vector_type(4))) unsigned short u16x4;
typedef __attribute__((ext_vector_type(4))) float f32x4;

__device__ __forceinline__ float bf2f(u16 u) {
    union { unsigned int i; float f; } v; v.i = ((unsigned int)u) << 16; return v.f;
}
__device__ __forceinline__ u16 f2bf(float f) {
    union { __hip_bfloat16 h; u16 u; } cv;
    cv.h = __float2bfloat16(f);
    return cv.u;
}
__device__ __forceinline__ float fast_tanh(float x) {
    float e = __expf(2.f * x);
    return (e - 1.f) / (e + 1.f);
}

#define TILE_M 128
#define TILE_N 128
#define TILE_K 32

// C(M,N) = A(M,K) @ Wt(N,K)^T (+bias). Double-buffered LDS + DEPTH-2 register
// prefetch: tile t+2's global loads issue at start of step t (in flight ~2 full
// phases before the vmcnt wait at store) — R5 was depth-1 and latency-bound
// (MfmaUtil 10%, 55% idle). Two named reg sets, no runtime indexing (rule #20).
// C_MODE: 0 = bf16 store, 1 = f32 store, 2 = f32 atomicAdd (split-K; exactly 2
// commutative adds onto memset-0 -> bitwise deterministic).
template<int A_F32, int HAS_BIAS, int C_MODE, int NGUARD>
__global__ __launch_bounds__(256)
void gemm_k(const void* __restrict__ Ap, const u16* __restrict__ Bt,
            const float* __restrict__ bias, void* __restrict__ Cp,
            int M, int N, int K, int lda, int ldc, int nt, int kchunk)
{
    __shared__ u16 As[2][TILE_M][TILE_K + 8];
    __shared__ u16 Bs[2][TILE_N][TILE_K + 8];

    const int nwg = gridDim.x;
    const int q = nwg >> 3, r = nwg & 7;
    const int xcd = blockIdx.x & 7, pos = blockIdx.x >> 3;
    const int wg = (xcd < r ? xcd * (q + 1) : r * (q + 1) + (xcd - r) * q) + pos;
    const int m0 = (wg / nt) * TILE_M;
    const int n0 = (wg % nt) * TILE_N;

    const int kc    = blockIdx.y;
    const int kbeg  = kc * kchunk;
    const int kend  = (kbeg + kchunk < K) ? kbeg + kchunk : K;
    const int steps = (kend - kbeg) / TILE_K;

    const int t    = threadIdx.x;
    const int lane = t & 63;
    const int w    = t >> 6;
    const int wm   = (w >> 1) * 64;
    const int wn   = (w & 1) * 64;
    const int lr   = lane & 15;
    const int kg   = (lane >> 4) * 8;

    const int srow = t >> 2;         // 0..63
    const int skc  = (t & 3) * 8;    // 0,8,16,24

    // two staging register sets (depth-2 pipeline)
    float4 pa0_0, pa1_0, pa2_0, pa3_0;  u16x8 qa0_0, qa1_0, qb0_0, qb1_0;
    float4 pa0_1, pa1_1, pa2_1, pa3_1;  u16x8 qa0_1, qa1_1, qb0_1, qb1_1;

#define LOAD_SET(S) \
    { \
        if (A_F32) { \
            const float* ap0 = (const float*)Ap + (size_t)(m0 + srow) * lda + k0_ + skc; \
            const float* ap1 = (const float*)Ap + (size_t)(m0 + srow + 64) * lda + k0_ + skc; \
            pa0_##S = *(const float4*)ap0; pa1_##S = *(const float4*)(ap0 + 4); \
            pa2_##S = *(const float4*)ap1; pa3_##S = *(const float4*)(ap1 + 4); \
        } else { \
            qa0_##S = *(const u16x8*)((const u16*)Ap + (size_t)(m0 + srow) * lda + k0_ + skc); \
            qa1_##S = *(const u16x8*)((const u16*)Ap + (size_t)(m0 + srow + 64) * lda + k0_ + skc); \
        } \
        u16x8 z = (u16x8){0,0,0,0,0,0,0,0}; \
        if (!NGUARD || n0 + srow < N) \
            qb0_##S = *(const u16x8*)(Bt + (size_t)(n0 + srow) * K + k0_ + skc); \
        else qb0_##S = z; \
        if (!NGUARD || n0 + srow + 64 < N) \
            qb1_##S = *(const u16x8*)(Bt + (size_t)(n0 + srow + 64) * K + k0_ + skc); \
        else qb1_##S = z; \
    }

#define STORE_SET(S, buf) \
    { \
        if (A_F32) { \
            u16x8 v0, v1; \
            v0[0] = f2bf(pa0_##S.x); v0[1] = f2bf(pa0_##S.y); v0[2] = f2bf(pa0_##S.z); v0[3] = f2bf(pa0_##S.w); \
            v0[4] = f2bf(pa1_##S.x); v0[5] = f2bf(pa1_##S.y); v0[6] = f2bf(pa1_##S.z); v0[7] = f2bf(pa1_##S.w); \
            v1[0] = f2bf(pa2_##S.x); v1[1] = f2bf(pa2_##S.y); v1[2] = f2bf(pa2_##S.z); v1[3] = f2bf(pa2_##S.w); \
            v1[4] = f2bf(pa3_##S.x); v1[5] = f2bf(pa3_##S.y); v1[6] = f2bf(pa3_##S.z); v1[7] = f2bf(pa3_##S.w); \
            *(u16x8*)&As[buf][srow][skc]      = v0; \
            *(u16x8*)&As[buf][srow + 64][skc] = v1; \
        } else { \
            *(u16x8*)&As[buf][srow][skc]      = qa0_##S; \
            *(u16x8*)&As[buf][srow + 64][skc] = qa1_##S; \
        } \
        *(u16x8*)&Bs[buf][srow][skc]      = qb0_##S; \
        *(u16x8*)&Bs[buf][srow + 64][skc] = qb1_##S; \
    }

    f32x4 acc[4][4];
#pragma unroll
    for (int i = 0; i < 4; ++i)
#pragma unroll
        for (int j = 0; j < 4; ++j) acc[i][j] = (f32x4){0.f, 0.f, 0.f, 0.f};

    // prologue: tile0 -> set0 (stored), tile1 -> set1 (in flight)
    { int k0_ = kbeg; LOAD_SET(0) }
    if (steps > 1) { int k0_ = kbeg + TILE_K; LOAD_SET(1) }
    STORE_SET(0, 0)
    __syncthreads();

    int cur = 0;
    for (int st = 0; st < steps; ++st) {
        // issue tile st+2 into the set freed at end of st-1 (set st&1)
        if (st + 2 < steps) {
            int k0_ = kbeg + (st + 2) * TILE_K;
            if ((st & 1) == 0) { LOAD_SET(0) } else { LOAD_SET(1) }
        }

        bfrag8 af[4], bfr[4];
#pragma unroll
        for (int mi = 0; mi < 4; ++mi) af[mi]  = *(const bfrag8*)&As[cur][wm + mi * 16 + lr][kg];
#pragma unroll
        for (int ni = 0; ni < 4; ++ni) bfr[ni] = *(const bfrag8*)&Bs[cur][wn + ni * 16 + lr][kg];
#pragma unroll
        for (int mi = 0; mi < 4; ++mi)
#pragma unroll
            for (int ni = 0; ni < 4; ++ni)
                acc[mi][ni] = __builtin_amdgcn_mfma_f32_16x16x32_bf16(af[mi], bfr[ni], acc[mi][ni], 0, 0, 0);

        // store tile st+1 (loaded 1.5 phases ago) to the other LDS buffer
        if (st + 1 < steps) {
            if (((st + 1) & 1) == 0) { STORE_SET(0, cur ^ 1) } else { STORE_SET(1, cur ^ 1) }
            __syncthreads();
            cur ^= 1;
        }
    }
#undef LOAD_SET
#undef STORE_SET

#pragma unroll
    for (int mi = 0; mi < 4; ++mi) {
#pragma unroll
        for (int ni = 0; ni < 4; ++ni) {
            int col = n0 + wn + ni * 16 + lr;
            if (!NGUARD || col < N) {
                int row = m0 + wm + mi * 16 + (lane >> 4) * 4;
                float bv = 0.f;
                if (HAS_BIAS && (C_MODE != 2 || kc == 0)) bv = bias[col];
#pragma unroll
                for (int rr = 0; rr < 4; ++rr) {
                    float v = acc[mi][ni][rr] + bv;
                    if (C_MODE == 0)      ((u16*)Cp)[(size_t)(row + rr) * ldc + col] = f2bf(v);
                    else if (C_MODE == 1) ((float*)Cp)[(size_t)(row + rr) * ldc + col] = v;
                    else                  atomicAdd((float*)Cp + (size_t)(row + rr) * ldc + col, v);
                }
            }
        }
    }
}

// scores[row][8] = [s_src h0..3, s_dst h0..3]; one wave per row of h (bf16).
__global__ __launch_bounds__(256)
void score_k(const u16* __restrict__ hs, int ld,
             const float* __restrict__ a_src, const float* __restrict__ a_dst,
             float* __restrict__ scores, int Mrows)
{
    const int wid  = blockIdx.x * 4 + (threadIdx.x >> 6);
    const int lane = threadIdx.x & 63;
    if (wid >= Mrows) return;
    const u16* hp = hs + (size_t)wid * ld + lane * 4;
    u16x4 xv = *(const u16x4*)hp;
    float s1 = 0.f, s2 = 0.f;
#pragma unroll
    for (int k = 0; k < 4; ++k) {
        float x = bf2f(xv[k]);
        s1 = fmaf(x, a_src[lane * 4 + k], s1);
        s2 = fmaf(x, a_dst[lane * 4 + k], s2);
    }
#pragma unroll
    for (int off = 1; off < 16; off <<= 1) {
        s1 += __shfl_xor(s1, off);
        s2 += __shfl_xor(s2, off);
    }
    if ((lane & 15) == 0) {
        scores[(size_t)wid * 8 + (lane >> 4)] = s1;
        scores[(size_t)wid * 8 + 4 + (lane >> 4)] = s2;
    }
}

// One thread per (b,h): full 7x7 leaky-relu + mask + top-3 + softmax.
template<int WRITE_ATTN>
__global__ __launch_bounds__(256)
void alpha_k(const float* __restrict__ scores, const float* __restrict__ em2,
             float* __restrict__ alpha, float* __restrict__ attn_out)
{
    const int t = blockIdx.x * 256 + threadIdx.x;
    const int b = t >> 2;
    const int h = t & 3;

    float ssrc[7], sdst[7];
#pragma unroll
    for (int n = 0; n < 7; ++n) {
        ssrc[n] = scores[(size_t)(b * 7 + n) * 8 + h];
        sdst[n] = scores[(size_t)(b * 7 + n) * 8 + 4 + h];
    }

    float al[49];
#pragma unroll
    for (int i = 0; i < 7; ++i) {
        float e[7];
#pragma unroll
        for (int j = 0; j < 7; ++j) {
            float v = ssrc[i] + sdst[j];
            v = fmaxf(v, 0.2f * v);
            e[j] = fmaf(v, em2[(i * 7 + j) * 2], em2[(i * 7 + j) * 2 + 1]);
        }
        float a1 = -3e38f, b1 = -3e38f, c1 = -3e38f;
#pragma unroll
        for (int j = 0; j < 7; ++j) {
            float v = e[j];
            float t2 = fminf(a1, v); a1 = fmaxf(a1, v);
            float t3 = fminf(b1, t2); b1 = fmaxf(b1, t2);
            c1 = fmaxf(c1, t3);
        }
        float psum = 0.f;
        float p[7];
#pragma unroll
        for (int j = 0; j < 7; ++j) {
            float qv = (e[j] >= c1) ? __expf(e[j] - a1) : 0.f;
            p[j] = qv; psum += qv;
        }
        float inv = 1.f / psum;
#pragma unroll
        for (int j = 0; j < 7; ++j) al[i * 7 + j] = p[j] * inv;
    }

    float* ap = alpha + (size_t)t * 49;
#pragma unroll
    for (int j = 0; j < 49; ++j) ap[j] = al[j];

    if (WRITE_ATTN) {
#pragma unroll
        for (int j = 0; j < 49; ++j) {
            float m = al[j];
            m += __shfl_xor(m, 1);
            m += __shfl_xor(m, 2);
            if (h == 0) attn_out[(size_t)b * 49 + j] = 0.25f * m;
        }
    }
}

// PV + residual + LN + relu. block=256: wave=head h, lane=d.
__global__ __launch_bounds__(256)
void gat_apply_k(const u16* __restrict__ hh, int ld_hh,
                 const u16* __restrict__ resid, int ld_res, int res_off,
                 const float* __restrict__ alpha,
                 const float* __restrict__ ln_w, const float* __restrict__ ln_b,
                 u16* __restrict__ outp, int out_bs)
{
    const int b = blockIdx.x;
    const int t = threadIdx.x;
    const int h = __builtin_amdgcn_readfirstlane(t >> 6);
    const int d = t & 63;
    const int c = (h << 6) + d;
    const size_t rowbase = (size_t)b * 7;

    float al[49];
    const float* ap = alpha + ((size_t)b * 4 + h) * 49;
#pragma unroll
    for (int j = 0; j < 49; ++j) al[j] = ap[j];

    float hv[7];
#pragma unroll
    for (int n = 0; n < 7; ++n) hv[n] = bf2f(hh[(rowbase + n) * ld_hh + c]);

    __shared__ float s_red[7][4][2];

    float xv[7];
#pragma unroll
    for (int i = 0; i < 7; ++i) {
        float pv = 0.f;
#pragma unroll
        for (int j = 0; j < 7; ++j) pv = fmaf(al[i * 7 + j], hv[j], pv);
        float x = pv + bf2f(resid[(rowbase + i) * ld_res + res_off + c]);
        xv[i] = x;
        float s1 = x, s2 = x * x;
#pragma unroll
        for (int off = 32; off > 0; off >>= 1) {
            s1 += __shfl_xor(s1, off);
            s2 += __shfl_xor(s2, off);
        }
        if (d == 0) { s_red[i][h][0] = s1; s_red[i][h][1] = s2; }
    }
    __syncthreads();
#pragma unroll
    for (int i = 0; i < 7; ++i) {
        float s1 = s_red[i][0][0] + s_red[i][1][0] + s_red[i][2][0] + s_red[i][3][0];
        float s2 = s_red[i][0][1] + s_red[i][1][1] + s_red[i][2][1] + s_red[i][3][1];
        float mu  = s1 * (1.f / 256.f);
        float var = fmaxf(s2 * (1.f / 256.f) - mu * mu, 0.f);
        float inv = rsqrtf(var + 1e-5f);
        float y = (xv[i] - mu) * inv * ln_w[c] + ln_b[c];
        y = fmaxf(y, 0.f);
        outp[(size_t)b * out_bs + i * 256 + c] = f2bf(y);
    }
}

// weight transpose/cast + bias fuse + edge_mask
__global__ __launch_bounds__(256)
void prep_k(const float* __restrict__ W1, const float* __restrict__ skip_w, const float* __restrict__ W2,
            const float* __restrict__ base_w1, const float* __restrict__ reg_w1, const float* __restrict__ res_w1,
            const float* __restrict__ skip_b, const float* __restrict__ base_b1, const float* __restrict__ reg_b1,
            const float* __restrict__ res_b1, const float* __restrict__ edge_logits,
            u16* __restrict__ Wt1, u16* __restrict__ Wt2, u16* __restrict__ Wt3,
            float* __restrict__ bias1, float* __restrict__ bias3,
            float* __restrict__ em2, float* __restrict__ em_out)
{
    int idx = blockIdx.x * 256 + threadIdx.x;
    if (idx < 512 * 256) {            // Wt1[n][k] = [W1|skip_w][k][n]
        int n = idx >> 8, k = idx & 255;
        float v = (n < 256) ? W1[k * 256 + n] : skip_w[k * 256 + (n - 256)];
        Wt1[n * 256 + k] = f2bf(v); return;
    }
    idx -= 512 * 256;
    if (idx < 256 * 256) {
        int n = idx >> 8, k = idx & 255;
        Wt2[n * 256 + k] = f2bf(W2[k * 256 + n]); return;
    }
    idx -= 256 * 256;
    if (idx < 80 * 1920) {            // Wt3[n][k] = [base_w1|reg_w1|res_w1][k][n]
        int n = idx / 1920, k = idx % 1920;
        float v = (n < 32) ? base_w1[k * 32 + n] : (n < 64) ? reg_w1[k * 32 + (n - 32)] : res_w1[k * 16 + (n - 64)];
        Wt3[n * 1920 + k] = f2bf(v); return;
    }
    idx -= 80 * 1920;
    if (idx < 512) { bias1[idx] = (idx < 256) ? 0.f : skip_b[idx - 256]; return; }
    idx -= 512;
    if (idx < 80) {
        bias3[idx] = (idx < 32) ? base_b1[idx] : (idx < 64) ? reg_b1[idx - 32] : res_b1[idx - 64];
        return;
    }
    idx -= 80;
    if (idx < 49) {
        int i = idx / 7, j = idx % 7;
        float s = 1.f / (1.f + __expf(-edge_logits[idx]));
        float m = (i == j) ? 1.f : s;
        em2[idx * 2] = m;
        em2[idx * 2 + 1] = (1.f - m) * (-1e9f);
        em_out[idx] = m;
    }
}

__global__ __launch_bounds__(256)
void ctx_k(const float* __restrict__ ctx, u16* __restrict__ comb)
{
    int idx = blockIdx.x * 256 + threadIdx.x;   // B*128
    int b = idx >> 7, cc = idx & 127;
    comb[(size_t)b * 1920 + 1792 + cc] = f2bf(ctx[idx]);
}

__global__ __launch_bounds__(256)
void head_finish(const float* __restrict__ ho, const float* __restrict__ bp, const float* __restrict__ rf,
                 const float* __restrict__ bw2, const float* __restrict__ bb2,
                 const float* __restrict__ rw2, const float* __restrict__ rb2,
                 const float* __restrict__ gw1, const float* __restrict__ gb1,
                 const float* __restrict__ gw2, const float* __restrict__ gb2,
                 const float* __restrict__ resw2, const float* __restrict__ resb2,
                 float* __restrict__ out_pred, float* __restrict__ out_w, float* __restrict__ out_gate, int B)
{
    int b = blockIdx.x * 256 + threadIdx.x;
    if (b >= B) return;
    const float* o = ho + (size_t)b * 80;

    float z0 = bb2[0], z1 = bb2[1];
#pragma unroll 8
    for (int k = 0; k < 32; ++k) { float v = fmaxf(o[k], 0.f); z0 += v * bw2[k * 2]; z1 += v * bw2[k * 2 + 1]; }
    float mz = fmaxf(z0, z1); float e0 = __expf(z0 - mz), e1 = __expf(z1 - mz); float inv = 1.f / (e0 + e1);
    float wb0 = e0 * inv, wb1 = e1 * inv;

    z0 = rb2[0]; z1 = rb2[1];
#pragma unroll 8
    for (int k = 0; k < 32; ++k) { float v = fmaxf(o[32 + k], 0.f); z0 += v * rw2[k * 2]; z1 += v * rw2[k * 2 + 1]; }
    mz = fmaxf(z0, z1); e0 = __expf(z0 - mz); e1 = __expf(z1 - mz); inv = 1.f / (e0 + e1);
    float wr0 = e0 * inv, wr1 = e1 * inv;

    float g = gb2[0];
#pragma unroll
    for (int j = 0; j < 8; ++j) {
        float a = gb1[j];
#pragma unroll
        for (int i = 0; i < 3; ++i) a += rf[(size_t)b * 3 + i] * gw1[i * 8 + j];
        g += fast_tanh(a) * gw2[j];
    }
    float gg = 1.f / (1.f + __expf(-g));
    float w0 = (1.f - gg) * wb0 + gg * wr0;
    float w1 = (1.f - gg) * wb1 + gg * wr1;
    float pred = w0 * bp[(size_t)b * 2] + w1 * bp[(size_t)b * 2 + 1];
    float r = resb2[0];
#pragma unroll 8
    for (int k = 0; k < 16; ++k) r += fast_tanh(o[64 + k]) * resw2[k];
    pred = fmaxf(pred + r * 0.05f, 0.05f);
    out_pred[b] = pred;
    out_w[(size_t)b * 2] = w0; out_w[(size_t)b * 2 + 1] = w1;
    out_gate[b] = gg;
}

extern "C" void kernel_launch(void* const* d_in, const int* in_sizes, int n_in,
                              void* d_out, int out_size, void* d_ws, size_t ws_size,
                              hipStream_t stream)
{
    const int B = in_sizes[1] / 128;     // context is (B,128)
    const int Mbig = B * 7;

    const float* node_feats   = (const float*)d_in[0];
    const float* context      = (const float*)d_in[1];
    const float* base_preds   = (const float*)d_in[2];
    const float* regime_feats = (const float*)d_in[3];
    const float* edge_logits  = (const float*)d_in[4];
    const float* W1      = (const float*)d_in[5];
    const float* a_src1  = (const float*)d_in[6];
    const float* a_dst1  = (const float*)d_in[7];
    const float* W2      = (const float*)d_in[8];
    const float* a_src2  = (const float*)d_in[9];
    const float* a_dst2  = (const float*)d_in[10];
    const float* ln1_w   = (const float*)d_in[11];
    const float* ln1_b   = (const float*)d_in[12];
    const float* ln2_w   = (const float*)d_in[13];
    const float* ln2_b   = (const float*)d_in[14];
    const float* skip_w  = (const float*)d_in[15];
    const float* skip_b  = (const float*)d_in[16];
    const float* base_w1 = (const float*)d_in[17];
    const float* base_b1 = (const float*)d_in[18];
    const float* base_w2 = (const float*)d_in[19];
    const float* base_b2 = (const float*)d_in[20];
    const float* reg_w1  = (const float*)d_in[21];
    const float* reg_b1  = (const float*)d_in[22];
    const float* reg_w2  = (const float*)d_in[23];
    const float* reg_b2  = (const float*)d_in[24];
    const float* gate_w1 = (const float*)d_in[25];
    const float* gate_b1 = (const float*)d_in[26];
    const float* gate_w2 = (const float*)d_in[27];
    const float* gate_b2 = (const float*)d_in[28];
    const float* res_w1  = (const float*)d_in[29];
    const float* res_b1  = (const float*)d_in[30];
    const float* res_w2  = (const float*)d_in[31];
    const float* res_b2  = (const float*)d_in[32];

    // workspace layout (bytes)
    char* ws = (char*)d_ws;
    size_t off = 0;
    u16* hs1 = (u16*)(ws + off);                       // [h1_pre|skip] Mbig x 512 bf16
    u16* hh2 = (u16*)(ws + off);                       // reuse after GAT1: Mbig x 256 bf16
    off += (size_t)Mbig * 512 * 2;
    u16* hbuf = (u16*)(ws + off);  off += (size_t)Mbig * 256 * 2;   // h: Mbig x 256 bf16
    u16* comb = (u16*)(ws + off);  off += (size_t)B * 1920 * 2;     // combined: B x 1920 bf16
    float* headout = (float*)(ws + off); off += (size_t)B * 80 * 4; // B x 80 f32
    u16* Wt1 = (u16*)(ws + off); off += 512 * 256 * 2;
    u16* Wt2 = (u16*)(ws + off); off += 256 * 256 * 2;
    u16* Wt3 = (u16*)(ws + off); off += (size_t)80 * 1920 * 2;
    float* bias1 = (float*)(ws + off); off += 512 * 4;
    float* bias3 = (float*)(ws + off); off += 128 * 4;
    float* em2   = (float*)(ws + off); off += 128 * 4;
    float* scoresb = (float*)(ws + off); off += (size_t)Mbig * 8 * 4;   // row scores f32
    float* alphab  = (float*)(ws + off); off += (size_t)B * 4 * 49 * 4; // alpha f32

    float* out_pred = (float*)d_out;
    float* out_w    = out_pred + B;
    float* out_gate = out_pred + 3 * (size_t)B;
    float* out_em   = out_pred + 4 * (size_t)B;
    float* out_attn = out_pred + 4 * (size_t)B + 49;

    const int B4blocks = (B * 4) / 256;

    // 1. weight prep + edge mask
    prep_k<<<dim3(1371), dim3(256), 0, stream>>>(W1, skip_w, W2, base_w1, reg_w1, res_w1,
        skip_b, base_b1, reg_b1, res_b1, edge_logits, Wt1, Wt2, Wt3, bias1, bias3, em2, out_em);

    // 2. GEMM1: node_feats(f32) @ [W1|skip_w] -> hs1 (bf16), bias=[0|skip_b]
    gemm_k<1, 1, 0, 0><<<dim3((Mbig / 128) * 4, 1), dim3(256), 0, stream>>>(
        (const void*)node_feats, Wt1, bias1, (void*)hs1, Mbig, 512, 256, 256, 512, 4, 256);

    // 3. scores from h1 (= hs1 cols 0..255)
    score_k<<<dim3(Mbig / 4), dim3(256), 0, stream>>>(hs1, 512, a_src1, a_dst1, scoresb, Mbig);

    // 4. alpha for GAT1
    alpha_k<0><<<dim3(B4blocks), dim3(256), 0, stream>>>(scoresb, em2, alphab, (float*)nullptr);

    // 5. GAT1 apply: PV + skip-resid + LN1 + relu -> hbuf
    gat_apply_k<<<dim3(B), dim3(256), 0, stream>>>(
        hs1, 512, hs1, 512, 256, alphab, ln1_w, ln1_b, hbuf, 1792);

    // 6. GEMM2: h @ W2 -> hh2 (reuses hs1 region)
    gemm_k<0, 0, 0, 0><<<dim3((Mbig / 128) * 2, 1), dim3(256), 0, stream>>>(
        (const void*)hbuf, Wt2, (const float*)nullptr, (void*)hh2, Mbig, 256, 256, 256, 256, 2, 256);

    // 7. scores from h2
    score_k<<<dim3(Mbig / 4), dim3(256), 0, stream>>>(hh2, 256, a_src2, a_dst2, scoresb, Mbig);

    // 8. alpha for GAT2 (+ attn mean output)
    alpha_k<1><<<dim3(B4blocks), dim3(256), 0, stream>>>(scoresb, em2, alphab, out_attn);

    // 9. GAT2 apply: PV + h-resid + LN2 + relu -> comb[:, :1792]
    gat_apply_k<<<dim3(B), dim3(256), 0, stream>>>(
        hh2, 256, hbuf, 256, 0, alphab, ln2_w, ln2_b, comb, 1920);

    // 10. context -> comb[:, 1792:]
    ctx_k<<<dim3(B * 128 / 256), dim3(256), 0, stream>>>(context, comb);

    // 11. GEMM3: comb @ [base_w1|reg_w1|res_w1] + bias -> headout (f32), split-K x2
    hipMemsetAsync(headout, 0, (size_t)B * 80 * 4, stream);
    gemm_k<0, 1, 2, 1><<<dim3(B / 128, 2), dim3(256), 0, stream>>>(
        (const void*)comb, Wt3, bias3, (void*)headout, B, 80, 1920, 1920, 80, 1, 960);

    // 12. heads -> pred, weights, gate
    head_finish<<<dim3((B + 255) / 256), dim3(256), 0, stream>>>(
        headout, base_preds, regime_feats, base_w2, base_b2, reg_w2, reg_b2,
        gate_w1, gate_b1, gate_w2, gate_b2, res_w2, res_b2, out_pred, out_w, out_gate, B);
}

// Round 7
// 373.811 us; speedup vs baseline: 1.0499x; 1.0444x over previous
//
#include <hip/hip_runtime.h>
#include <hip/hip_bf16.h>

typedef unsigned short u16;
typedef __attribute__((ext_vector_type(8))) short bfrag8;
typedef __attribute__((ext_vector_type(8))) unsigned short u16x8;
typedef __attribute__((ext_vector_type(4))) unsigned short u16x4;
typedef __attribute__((ext_vector_type(4))) float f32x4;

__device__ __forceinline__ float bf2f(u16 u) {
    union { unsigned int i; float f; } v; v.i = ((unsigned int)u) << 16; return v.f;
}
__device__ __forceinline__ u16 f2bf(float f) {
    union { __hip_bfloat16 h; u16 u; } cv;
    cv.h = __float2bfloat16(f);
    return cv.u;
}
__device__ __forceinline__ float fast_tanh(float x) {
    float e = __expf(2.f * x);
    return (e - 1.f) / (e + 1.f);
}

#define TILE_M 128
#define TILE_N 128
#define TILE_K 32

#define GLOAD_LDS16(g, l) \
    __builtin_amdgcn_global_load_lds( \
        (const __attribute__((address_space(1))) void*)(g), \
        (__attribute__((address_space(3))) void*)(l), 16, 0, 0)

// C(M,N) = A(M,K)bf16 @ Wt(N,K)^T (+bias). m97 structure: single-buffered
// linear LDS [128][32], global_load_lds width=16 staging (R6's reg-staged path
// was 3x slower per K-step — compiler re-serializes source-level prefetch; the
// DMA path is the guide-proven fix, m151/m97). XCD-chunk swizzle (m204).
// C_MODE: 0 = bf16 store, 1 = f32 store, 2 = f32 atomicAdd (split-K; exactly 2
// commutative adds onto memset-0 -> bitwise deterministic).
// NGUARD guards the C store only; B rows must be padded to TILE_N by caller.
template<int HAS_BIAS, int C_MODE, int NGUARD>
__global__ __launch_bounds__(256)
void gemm_k(const u16* __restrict__ A, const u16* __restrict__ Bt,
            const float* __restrict__ bias, void* __restrict__ Cp,
            int M, int N, int K, int lda, int ldc, int nt, int kchunk)
{
    __shared__ u16 As[TILE_M][TILE_K];   // 8 KB, linear: global_load_lds dest is base+lane*16
    __shared__ u16 Bs[TILE_N][TILE_K];

    const int nwg = gridDim.x;
    const int q = nwg >> 3, r = nwg & 7;
    const int xcd = blockIdx.x & 7, pos = blockIdx.x >> 3;
    const int wg = (xcd < r ? xcd * (q + 1) : r * (q + 1) + (xcd - r) * q) + pos;
    const int m0 = (wg / nt) * TILE_M;
    const int n0 = (wg % nt) * TILE_N;

    const int kc   = blockIdx.y;
    const int kbeg = kc * kchunk;
    const int kend = (kbeg + kchunk < K) ? kbeg + kchunk : K;

    const int t    = threadIdx.x;
    const int lane = t & 63;
    const int w    = t >> 6;
    const int wm   = (w >> 1) * 64;
    const int wn   = (w & 1) * 64;
    const int lr   = lane & 15;
    const int kg   = (lane >> 4) * 8;

    // loader mapping: wave w covers 32 rows (2 issues x 16 rows); lane l ->
    // row 32w + 16j + (l>>2), halfword col (l&3)*8; LDS lands linearly.
    const int lrow = lane >> 2;          // 0..15
    const int lcol = (lane & 3) * 8;     // 0,8,16,24
    const u16* gA0 = A  + (size_t)(m0 + 32 * w + lrow) * lda + lcol;
    const u16* gA1 = gA0 + (size_t)16 * lda;
    const u16* gB0 = Bt + (size_t)(n0 + 32 * w + lrow) * K + lcol;
    const u16* gB1 = gB0 + (size_t)16 * K;
    char* lA0 = (char*)&As[0][0] + w * 2048;
    char* lA1 = lA0 + 1024;
    char* lB0 = (char*)&Bs[0][0] + w * 2048;
    char* lB1 = lB0 + 1024;

    f32x4 acc[4][4];
#pragma unroll
    for (int i = 0; i < 4; ++i)
#pragma unroll
        for (int j = 0; j < 4; ++j) acc[i][j] = (f32x4){0.f, 0.f, 0.f, 0.f};

    for (int k0 = kbeg; k0 < kend; k0 += TILE_K) {
        GLOAD_LDS16(gA0 + k0, lA0);
        GLOAD_LDS16(gA1 + k0, lA1);
        GLOAD_LDS16(gB0 + k0, lB0);
        GLOAD_LDS16(gB1 + k0, lB1);
        asm volatile("s_waitcnt vmcnt(0)" ::: "memory");
        __syncthreads();

        bfrag8 af[4], bfr[4];
#pragma unroll
        for (int mi = 0; mi < 4; ++mi) af[mi]  = *(const bfrag8*)&As[wm + mi * 16 + lr][kg];
#pragma unroll
        for (int ni = 0; ni < 4; ++ni) bfr[ni] = *(const bfrag8*)&Bs[wn + ni * 16 + lr][kg];
#pragma unroll
        for (int mi = 0; mi < 4; ++mi)
#pragma unroll
            for (int ni = 0; ni < 4; ++ni)
                acc[mi][ni] = __builtin_amdgcn_mfma_f32_16x16x32_bf16(af[mi], bfr[ni], acc[mi][ni], 0, 0, 0);

        __syncthreads();   // protect LDS from next iteration's DMA
    }

#pragma unroll
    for (int mi = 0; mi < 4; ++mi) {
#pragma unroll
        for (int ni = 0; ni < 4; ++ni) {
            int col = n0 + wn + ni * 16 + lr;
            if (!NGUARD || col < N) {
                int row = m0 + wm + mi * 16 + (lane >> 4) * 4;
                float bv = 0.f;
                if (HAS_BIAS && (C_MODE != 2 || kc == 0)) bv = bias[col];
#pragma unroll
                for (int rr = 0; rr < 4; ++rr) {
                    float v = acc[mi][ni][rr] + bv;
                    if (C_MODE == 0)      ((u16*)Cp)[(size_t)(row + rr) * ldc + col] = f2bf(v);
                    else if (C_MODE == 1) ((float*)Cp)[(size_t)(row + rr) * ldc + col] = v;
                    else                  atomicAdd((float*)Cp + (size_t)(row + rr) * ldc + col, v);
                }
            }
        }
    }
}

// f32 -> bf16 streaming cast (HBM-bound), 8 elems/thread.
__global__ __launch_bounds__(256)
void precast_k(const float* __restrict__ in, u16* __restrict__ out, int n8)
{
    int i = blockIdx.x * 256 + threadIdx.x;
    if (i >= n8) return;
    const float4* p = (const float4*)(in + (size_t)i * 8);
    float4 a = p[0], b = p[1];
    u16x8 v;
    v[0] = f2bf(a.x); v[1] = f2bf(a.y); v[2] = f2bf(a.z); v[3] = f2bf(a.w);
    v[4] = f2bf(b.x); v[5] = f2bf(b.y); v[6] = f2bf(b.z); v[7] = f2bf(b.w);
    *(u16x8*)(out + (size_t)i * 8) = v;
}

// scores[row][8] = [s_src h0..3, s_dst h0..3]; one wave per row of h (bf16).
__global__ __launch_bounds__(256)
void score_k(const u16* __restrict__ hs, int ld,
             const float* __restrict__ a_src, const float* __restrict__ a_dst,
             float* __restrict__ scores, int Mrows)
{
    const int wid  = blockIdx.x * 4 + (threadIdx.x >> 6);
    const int lane = threadIdx.x & 63;
    if (wid >= Mrows) return;
    const u16* hp = hs + (size_t)wid * ld + lane * 4;
    u16x4 xv = *(const u16x4*)hp;
    float s1 = 0.f, s2 = 0.f;
#pragma unroll
    for (int k = 0; k < 4; ++k) {
        float x = bf2f(xv[k]);
        s1 = fmaf(x, a_src[lane * 4 + k], s1);
        s2 = fmaf(x, a_dst[lane * 4 + k], s2);
    }
#pragma unroll
    for (int off = 1; off < 16; off <<= 1) {
        s1 += __shfl_xor(s1, off);
        s2 += __shfl_xor(s2, off);
    }
    if ((lane & 15) == 0) {
        scores[(size_t)wid * 8 + (lane >> 4)] = s1;
        scores[(size_t)wid * 8 + 4 + (lane >> 4)] = s2;
    }
}

// One thread per (b,h): full 7x7 leaky-relu + mask + top-3 + softmax.
template<int WRITE_ATTN>
__global__ __launch_bounds__(256)
void alpha_k(const float* __restrict__ scores, const float* __restrict__ em2,
             float* __restrict__ alpha, float* __restrict__ attn_out)
{
    const int t = blockIdx.x * 256 + threadIdx.x;
    const int b = t >> 2;
    const int h = t & 3;

    float ssrc[7], sdst[7];
#pragma unroll
    for (int n = 0; n < 7; ++n) {
        ssrc[n] = scores[(size_t)(b * 7 + n) * 8 + h];
        sdst[n] = scores[(size_t)(b * 7 + n) * 8 + 4 + h];
    }

    float al[49];
#pragma unroll
    for (int i = 0; i < 7; ++i) {
        float e[7];
#pragma unroll
        for (int j = 0; j < 7; ++j) {
            float v = ssrc[i] + sdst[j];
            v = fmaxf(v, 0.2f * v);
            e[j] = fmaf(v, em2[(i * 7 + j) * 2], em2[(i * 7 + j) * 2 + 1]);
        }
        float a1 = -3e38f, b1 = -3e38f, c1 = -3e38f;
#pragma unroll
        for (int j = 0; j < 7; ++j) {
            float v = e[j];
            float t2 = fminf(a1, v); a1 = fmaxf(a1, v);
            float t3 = fminf(b1, t2); b1 = fmaxf(b1, t2);
            c1 = fmaxf(c1, t3);
        }
        float psum = 0.f;
        float p[7];
#pragma unroll
        for (int j = 0; j < 7; ++j) {
            float qv = (e[j] >= c1) ? __expf(e[j] - a1) : 0.f;
            p[j] = qv; psum += qv;
        }
        float inv = 1.f / psum;
#pragma unroll
        for (int j = 0; j < 7; ++j) al[i * 7 + j] = p[j] * inv;
    }

    float* ap = alpha + (size_t)t * 49;
#pragma unroll
    for (int j = 0; j < 49; ++j) ap[j] = al[j];

    if (WRITE_ATTN) {
#pragma unroll
        for (int j = 0; j < 49; ++j) {
            float m = al[j];
            m += __shfl_xor(m, 1);
            m += __shfl_xor(m, 2);
            if (h == 0) attn_out[(size_t)b * 49 + j] = 0.25f * m;
        }
    }
}

// PV + residual + LN + relu. block=256: wave=head h, lane=d.
__global__ __launch_bounds__(256)
void gat_apply_k(const u16* __restrict__ hh, int ld_hh,
                 const u16* __restrict__ resid, int ld_res, int res_off,
                 const float* __restrict__ alpha,
                 const float* __restrict__ ln_w, const float* __restrict__ ln_b,
                 u16* __restrict__ outp, int out_bs)
{
    const int b = blockIdx.x;
    const int t = threadIdx.x;
    const int h = __builtin_amdgcn_readfirstlane(t >> 6);
    const int d = t & 63;
    const int c = (h << 6) + d;
    const size_t rowbase = (size_t)b * 7;

    float al[49];
    const float* ap = alpha + ((size_t)b * 4 + h) * 49;
#pragma unroll
    for (int j = 0; j < 49; ++j) al[j] = ap[j];

    float hv[7];
#pragma unroll
    for (int n = 0; n < 7; ++n) hv[n] = bf2f(hh[(rowbase + n) * ld_hh + c]);

    __shared__ float s_red[7][4][2];

    float xv[7];
#pragma unroll
    for (int i = 0; i < 7; ++i) {
        float pv = 0.f;
#pragma unroll
        for (int j = 0; j < 7; ++j) pv = fmaf(al[i * 7 + j], hv[j], pv);
        float x = pv + bf2f(resid[(rowbase + i) * ld_res + res_off + c]);
        xv[i] = x;
        float s1 = x, s2 = x * x;
#pragma unroll
        for (int off = 32; off > 0; off >>= 1) {
            s1 += __shfl_xor(s1, off);
            s2 += __shfl_xor(s2, off);
        }
        if (d == 0) { s_red[i][h][0] = s1; s_red[i][h][1] = s2; }
    }
    __syncthreads();
#pragma unroll
    for (int i = 0; i < 7; ++i) {
        float s1 = s_red[i][0][0] + s_red[i][1][0] + s_red[i][2][0] + s_red[i][3][0];
        float s2 = s_red[i][0][1] + s_red[i][1][1] + s_red[i][2][1] + s_red[i][3][1];
        float mu  = s1 * (1.f / 256.f);
        float var = fmaxf(s2 * (1.f / 256.f) - mu * mu, 0.f);
        float inv = rsqrtf(var + 1e-5f);
        float y = (xv[i] - mu) * inv * ln_w[c] + ln_b[c];
        y = fmaxf(y, 0.f);
        outp[(size_t)b * out_bs + i * 256 + c] = f2bf(y);
    }
}

// weight transpose/cast + bias fuse + edge_mask. Wt3 padded to 128 rows (zeros)
// so the padded GEMM3 loader needs no bounds checks.
__global__ __launch_bounds__(256)
void prep_k(const float* __restrict__ W1, const float* __restrict__ skip_w, const float* __restrict__ W2,
            const float* __restrict__ base_w1, const float* __restrict__ reg_w1, const float* __restrict__ res_w1,
            const float* __restrict__ skip_b, const float* __restrict__ base_b1, const float* __restrict__ reg_b1,
            const float* __restrict__ res_b1, const float* __restrict__ edge_logits,
            u16* __restrict__ Wt1, u16* __restrict__ Wt2, u16* __restrict__ Wt3,
            float* __restrict__ bias1, float* __restrict__ bias3,
            float* __restrict__ em2, float* __restrict__ em_out)
{
    int idx = blockIdx.x * 256 + threadIdx.x;
    if (idx < 512 * 256) {            // Wt1[n][k] = [W1|skip_w][k][n]
        int n = idx >> 8, k = idx & 255;
        float v = (n < 256) ? W1[k * 256 + n] : skip_w[k * 256 + (n - 256)];
        Wt1[n * 256 + k] = f2bf(v); return;
    }
    idx -= 512 * 256;
    if (idx < 256 * 256) {
        int n = idx >> 8, k = idx & 255;
        Wt2[n * 256 + k] = f2bf(W2[k * 256 + n]); return;
    }
    idx -= 256 * 256;
    if (idx < 128 * 1920) {           // Wt3[n][k] = [base_w1|reg_w1|res_w1][k][n], rows 80..127 zero
        int n = idx / 1920, k = idx % 1920;
        float v = (n < 32) ? base_w1[k * 32 + n]
                : (n < 64) ? reg_w1[k * 32 + (n - 32)]
                : (n < 80) ? res_w1[k * 16 + (n - 64)] : 0.f;
        Wt3[n * 1920 + k] = f2bf(v); return;
    }
    idx -= 128 * 1920;
    if (idx < 512) { bias1[idx] = (idx < 256) ? 0.f : skip_b[idx - 256]; return; }
    idx -= 512;
    if (idx < 80) {
        bias3[idx] = (idx < 32) ? base_b1[idx] : (idx < 64) ? reg_b1[idx - 32] : res_b1[idx - 64];
        return;
    }
    idx -= 80;
    if (idx < 49) {
        int i = idx / 7, j = idx % 7;
        float s = 1.f / (1.f + __expf(-edge_logits[idx]));
        float m = (i == j) ? 1.f : s;
        em2[idx * 2] = m;
        em2[idx * 2 + 1] = (1.f - m) * (-1e9f);
        em_out[idx] = m;
    }
}

__global__ __launch_bounds__(256)
void ctx_k(const float* __restrict__ ctx, u16* __restrict__ comb)
{
    int idx = blockIdx.x * 256 + threadIdx.x;   // B*128
    int b = idx >> 7, cc = idx & 127;
    comb[(size_t)b * 1920 + 1792 + cc] = f2bf(ctx[idx]);
}

__global__ __launch_bounds__(256)
void head_finish(const float* __restrict__ ho, const float* __restrict__ bp, const float* __restrict__ rf,
                 const float* __restrict__ bw2, const float* __restrict__ bb2,
                 const float* __restrict__ rw2, const float* __restrict__ rb2,
                 const float* __restrict__ gw1, const float* __restrict__ gb1,
                 const float* __restrict__ gw2, const float* __restrict__ gb2,
                 const float* __restrict__ resw2, const float* __restrict__ resb2,
                 float* __restrict__ out_pred, float* __restrict__ out_w, float* __restrict__ out_gate, int B)
{
    int b = blockIdx.x * 256 + threadIdx.x;
    if (b >= B) return;
    const float* o = ho + (size_t)b * 80;

    float z0 = bb2[0], z1 = bb2[1];
#pragma unroll 8
    for (int k = 0; k < 32; ++k) { float v = fmaxf(o[k], 0.f); z0 += v * bw2[k * 2]; z1 += v * bw2[k * 2 + 1]; }
    float mz = fmaxf(z0, z1); float e0 = __expf(z0 - mz), e1 = __expf(z1 - mz); float inv = 1.f / (e0 + e1);
    float wb0 = e0 * inv, wb1 = e1 * inv;

    z0 = rb2[0]; z1 = rb2[1];
#pragma unroll 8
    for (int k = 0; k < 32; ++k) { float v = fmaxf(o[32 + k], 0.f); z0 += v * rw2[k * 2]; z1 += v * rw2[k * 2 + 1]; }
    mz = fmaxf(z0, z1); e0 = __expf(z0 - mz); e1 = __expf(z1 - mz); inv = 1.f / (e0 + e1);
    float wr0 = e0 * inv, wr1 = e1 * inv;

    float g = gb2[0];
#pragma unroll
    for (int j = 0; j < 8; ++j) {
        float a = gb1[j];
#pragma unroll
        for (int i = 0; i < 3; ++i) a += rf[(size_t)b * 3 + i] * gw1[i * 8 + j];
        g += fast_tanh(a) * gw2[j];
    }
    float gg = 1.f / (1.f + __expf(-g));
    float w0 = (1.f - gg) * wb0 + gg * wr0;
    float w1 = (1.f - gg) * wb1 + gg * wr1;
    float pred = w0 * bp[(size_t)b * 2] + w1 * bp[(size_t)b * 2 + 1];
    float r = resb2[0];
#pragma unroll 8
    for (int k = 0; k < 16; ++k) r += fast_tanh(o[64 + k]) * resw2[k];
    pred = fmaxf(pred + r * 0.05f, 0.05f);
    out_pred[b] = pred;
    out_w[(size_t)b * 2] = w0; out_w[(size_t)b * 2 + 1] = w1;
    out_gate[b] = gg;
}

extern "C" void kernel_launch(void* const* d_in, const int* in_sizes, int n_in,
                              void* d_out, int out_size, void* d_ws, size_t ws_size,
                              hipStream_t stream)
{
    const int B = in_sizes[1] / 128;     // context is (B,128)
    const int Mbig = B * 7;

    const float* node_feats   = (const float*)d_in[0];
    const float* context      = (const float*)d_in[1];
    const float* base_preds   = (const float*)d_in[2];
    const float* regime_feats = (const float*)d_in[3];
    const float* edge_logits  = (const float*)d_in[4];
    const float* W1      = (const float*)d_in[5];
    const float* a_src1  = (const float*)d_in[6];
    const float* a_dst1  = (const float*)d_in[7];
    const float* W2      = (const float*)d_in[8];
    const float* a_src2  = (const float*)d_in[9];
    const float* a_dst2  = (const float*)d_in[10];
    const float* ln1_w   = (const float*)d_in[11];
    const float* ln1_b   = (const float*)d_in[12];
    const float* ln2_w   = (const float*)d_in[13];
    const float* ln2_b   = (const float*)d_in[14];
    const float* skip_w  = (const float*)d_in[15];
    const float* skip_b  = (const float*)d_in[16];
    const float* base_w1 = (const float*)d_in[17];
    const float* base_b1 = (const float*)d_in[18];
    const float* base_w2 = (const float*)d_in[19];
    const float* base_b2 = (const float*)d_in[20];
    const float* reg_w1  = (const float*)d_in[21];
    const float* reg_b1  = (const float*)d_in[22];
    const float* reg_w2  = (const float*)d_in[23];
    const float* reg_b2  = (const float*)d_in[24];
    const float* gate_w1 = (const float*)d_in[25];
    const float* gate_b1 = (const float*)d_in[26];
    const float* gate_w2 = (const float*)d_in[27];
    const float* gate_b2 = (const float*)d_in[28];
    const float* res_w1  = (const float*)d_in[29];
    const float* res_b1  = (const float*)d_in[30];
    const float* res_w2  = (const float*)d_in[31];
    const float* res_b2  = (const float*)d_in[32];

    // workspace layout (bytes)
    char* ws = (char*)d_ws;
    size_t off = 0;
    u16* hs1 = (u16*)(ws + off);                       // [h1_pre|skip] Mbig x 512 bf16
    u16* hh2 = (u16*)(ws + off);                       // reuse after GAT1: Mbig x 256 bf16
    off += (size_t)Mbig * 512 * 2;
    u16* hbuf = (u16*)(ws + off);  off += (size_t)Mbig * 256 * 2;   // h: Mbig x 256 bf16
    u16* comb = (u16*)(ws + off);  off += (size_t)B * 1920 * 2;     // combined: B x 1920 bf16
    u16* nf_bf = comb;             // A1 bf16 (Mbig x 256, 59MB) aliases comb (63MB; dead until step 9)
    float* headout = (float*)(ws + off); off += (size_t)B * 80 * 4; // B x 80 f32
    u16* Wt1 = (u16*)(ws + off); off += 512 * 256 * 2;
    u16* Wt2 = (u16*)(ws + off); off += 256 * 256 * 2;
    u16* Wt3 = (u16*)(ws + off); off += (size_t)128 * 1920 * 2;     // padded to 128 rows
    float* bias1 = (float*)(ws + off); off += 512 * 4;
    float* bias3 = (float*)(ws + off); off += 128 * 4;
    float* em2   = (float*)(ws + off); off += 128 * 4;
    float* scoresb = (float*)(ws + off); off += (size_t)Mbig * 8 * 4;   // row scores f32
    float* alphab  = (float*)(ws + off); off += (size_t)B * 4 * 49 * 4; // alpha f32

    float* out_pred = (float*)d_out;
    float* out_w    = out_pred + B;
    float* out_gate = out_pred + 3 * (size_t)B;
    float* out_em   = out_pred + 4 * (size_t)B;
    float* out_attn = out_pred + 4 * (size_t)B + 49;

    const int B4blocks = (B * 4) / 256;

    // 0. node_feats f32 -> bf16 (HBM-bound streaming pass)
    {
        int n8 = Mbig * 256 / 8;
        precast_k<<<dim3((n8 + 255) / 256), dim3(256), 0, stream>>>(node_feats, nf_bf, n8);
    }

    // 1. weight prep + edge mask
    prep_k<<<dim3(1731), dim3(256), 0, stream>>>(W1, skip_w, W2, base_w1, reg_w1, res_w1,
        skip_b, base_b1, reg_b1, res_b1, edge_logits, Wt1, Wt2, Wt3, bias1, bias3, em2, out_em);

    // 2. GEMM1: nf_bf @ [W1|skip_w] -> hs1 (bf16), bias=[0|skip_b]
    gemm_k<1, 0, 0><<<dim3((Mbig / 128) * 4, 1), dim3(256), 0, stream>>>(
        nf_bf, Wt1, bias1, (void*)hs1, Mbig, 512, 256, 256, 512, 4, 256);

    // 3. scores from h1 (= hs1 cols 0..255)
    score_k<<<dim3(Mbig / 4), dim3(256), 0, stream>>>(hs1, 512, a_src1, a_dst1, scoresb, Mbig);

    // 4. alpha for GAT1
    alpha_k<0><<<dim3(B4blocks), dim3(256), 0, stream>>>(scoresb, em2, alphab, (float*)nullptr);

    // 5. GAT1 apply: PV + skip-resid + LN1 + relu -> hbuf
    gat_apply_k<<<dim3(B), dim3(256), 0, stream>>>(
        hs1, 512, hs1, 512, 256, alphab, ln1_w, ln1_b, hbuf, 1792);

    // 6. GEMM2: h @ W2 -> hh2 (reuses hs1 region)
    gemm_k<0, 0, 0><<<dim3((Mbig / 128) * 2, 1), dim3(256), 0, stream>>>(
        hbuf, Wt2, (const float*)nullptr, (void*)hh2, Mbig, 256, 256, 256, 256, 2, 256);

    // 7. scores from h2
    score_k<<<dim3(Mbig / 4), dim3(256), 0, stream>>>(hh2, 256, a_src2, a_dst2, scoresb, Mbig);

    // 8. alpha for GAT2 (+ attn mean output)
    alpha_k<1><<<dim3(B4blocks), dim3(256), 0, stream>>>(scoresb, em2, alphab, out_attn);

    // 9. GAT2 apply: PV + h-resid + LN2 + relu -> comb[:, :1792] (kills nf_bf alias)
    gat_apply_k<<<dim3(B), dim3(256), 0, stream>>>(
        hh2, 256, hbuf, 256, 0, alphab, ln2_w, ln2_b, comb, 1920);

    // 10. context -> comb[:, 1792:]
    ctx_k<<<dim3(B * 128 / 256), dim3(256), 0, stream>>>(context, comb);

    // 11. GEMM3: comb @ padded-Wt3 + bias -> headout (f32), split-K x2
    hipMemsetAsync(headout, 0, (size_t)B * 80 * 4, stream);
    gemm_k<1, 2, 1><<<dim3(B / 128, 2), dim3(256), 0, stream>>>(
        comb, Wt3, bias3, (void*)headout, B, 80, 1920, 1920, 80, 1, 960);

    // 12. heads -> pred, weights, gate
    head_finish<<<dim3((B + 255) / 256), dim3(256), 0, stream>>>(
        headout, base_preds, regime_feats, base_w2, base_b2, reg_w2, reg_b2,
        gate_w1, gate_b1, gate_w2, gate_b2, res_w2, res_b2, out_pred, out_w, out_gate, B);
}

// Round 8
// 298.120 us; speedup vs baseline: 1.3165x; 1.2539x over previous
//
#include <hip/hip_runtime.h>
#include <hip/hip_bf16.h>

typedef unsigned short u16;
typedef __attribute__((ext_vector_type(8))) short bfrag8;
typedef __attribute__((ext_vector_type(8))) unsigned short u16x8;
typedef __attribute__((ext_vector_type(4))) unsigned short u16x4;
typedef __attribute__((ext_vector_type(4))) float f32x4;

__device__ __forceinline__ float bf2f(u16 u) {
    union { unsigned int i; float f; } v; v.i = ((unsigned int)u) << 16; return v.f;
}
__device__ __forceinline__ u16 f2bf(float f) {
    union { __hip_bfloat16 h; u16 u; } cv;
    cv.h = __float2bfloat16(f);
    return cv.u;
}
__device__ __forceinline__ float fast_tanh(float x) {
    float e = __expf(2.f * x);
    return (e - 1.f) / (e + 1.f);
}

#define TILE_M 128
#define TILE_N 128
#define TILE_K 32

#define GLOAD_LDS16(g, l) \
    __builtin_amdgcn_global_load_lds( \
        (const __attribute__((address_space(1))) void*)(g), \
        (__attribute__((address_space(3))) void*)(l), 16, 0, 0)

// C(M,N) = A(M,K)bf16 @ Wt(N,K)^T (+bias). m97 structure: single-buffered
// linear LDS, global_load_lds width=16 staging. XCD-chunk swizzle (m204).
// C_MODE: 0 = bf16 store, 1 = f32 store, 2 = f32 atomicAdd (split-K).
template<int HAS_BIAS, int C_MODE, int NGUARD>
__global__ __launch_bounds__(256)
void gemm_k(const u16* __restrict__ A, const u16* __restrict__ Bt,
            const float* __restrict__ bias, void* __restrict__ Cp,
            int M, int N, int K, int lda, int ldc, int nt, int kchunk)
{
    __shared__ u16 As[TILE_M][TILE_K];
    __shared__ u16 Bs[TILE_N][TILE_K];

    const int nwg = gridDim.x;
    const int q = nwg >> 3, r = nwg & 7;
    const int xcd = blockIdx.x & 7, pos = blockIdx.x >> 3;
    const int wg = (xcd < r ? xcd * (q + 1) : r * (q + 1) + (xcd - r) * q) + pos;
    const int m0 = (wg / nt) * TILE_M;
    const int n0 = (wg % nt) * TILE_N;

    const int kc   = blockIdx.y;
    const int kbeg = kc * kchunk;
    const int kend = (kbeg + kchunk < K) ? kbeg + kchunk : K;

    const int t    = threadIdx.x;
    const int lane = t & 63;
    const int w    = t >> 6;
    const int wm   = (w >> 1) * 64;
    const int wn   = (w & 1) * 64;
    const int lr   = lane & 15;
    const int kg   = (lane >> 4) * 8;

    const int lrow = lane >> 2;          // 0..15
    const int lcol = (lane & 3) * 8;     // 0,8,16,24
    const u16* gA0 = A  + (size_t)(m0 + 32 * w + lrow) * lda + lcol;
    const u16* gA1 = gA0 + (size_t)16 * lda;
    const u16* gB0 = Bt + (size_t)(n0 + 32 * w + lrow) * K + lcol;
    const u16* gB1 = gB0 + (size_t)16 * K;
    char* lA0 = (char*)&As[0][0] + w * 2048;
    char* lA1 = lA0 + 1024;
    char* lB0 = (char*)&Bs[0][0] + w * 2048;
    char* lB1 = lB0 + 1024;

    f32x4 acc[4][4];
#pragma unroll
    for (int i = 0; i < 4; ++i)
#pragma unroll
        for (int j = 0; j < 4; ++j) acc[i][j] = (f32x4){0.f, 0.f, 0.f, 0.f};

    for (int k0 = kbeg; k0 < kend; k0 += TILE_K) {
        GLOAD_LDS16(gA0 + k0, lA0);
        GLOAD_LDS16(gA1 + k0, lA1);
        GLOAD_LDS16(gB0 + k0, lB0);
        GLOAD_LDS16(gB1 + k0, lB1);
        asm volatile("s_waitcnt vmcnt(0)" ::: "memory");
        __syncthreads();

        bfrag8 af[4], bfr[4];
#pragma unroll
        for (int mi = 0; mi < 4; ++mi) af[mi]  = *(const bfrag8*)&As[wm + mi * 16 + lr][kg];
#pragma unroll
        for (int ni = 0; ni < 4; ++ni) bfr[ni] = *(const bfrag8*)&Bs[wn + ni * 16 + lr][kg];
#pragma unroll
        for (int mi = 0; mi < 4; ++mi)
#pragma unroll
            for (int ni = 0; ni < 4; ++ni)
                acc[mi][ni] = __builtin_amdgcn_mfma_f32_16x16x32_bf16(af[mi], bfr[ni], acc[mi][ni], 0, 0, 0);

        __syncthreads();
    }

#pragma unroll
    for (int mi = 0; mi < 4; ++mi) {
#pragma unroll
        for (int ni = 0; ni < 4; ++ni) {
            int col = n0 + wn + ni * 16 + lr;
            if (!NGUARD || col < N) {
                int row = m0 + wm + mi * 16 + (lane >> 4) * 4;
                float bv = 0.f;
                if (HAS_BIAS && (C_MODE != 2 || kc == 0)) bv = bias[col];
#pragma unroll
                for (int rr = 0; rr < 4; ++rr) {
                    float v = acc[mi][ni][rr] + bv;
                    if (C_MODE == 0)      ((u16*)Cp)[(size_t)(row + rr) * ldc + col] = f2bf(v);
                    else if (C_MODE == 1) ((float*)Cp)[(size_t)(row + rr) * ldc + col] = v;
                    else                  atomicAdd((float*)Cp + (size_t)(row + rr) * ldc + col, v);
                }
            }
        }
    }
}

// f32 -> bf16 streaming cast (HBM-bound), 8 elems/thread.
__global__ __launch_bounds__(256)
void precast_k(const float* __restrict__ in, u16* __restrict__ out, int n8)
{
    int i = blockIdx.x * 256 + threadIdx.x;
    if (i >= n8) return;
    const float4* p = (const float4*)(in + (size_t)i * 8);
    float4 a = p[0], b = p[1];
    u16x8 v;
    v[0] = f2bf(a.x); v[1] = f2bf(a.y); v[2] = f2bf(a.z); v[3] = f2bf(a.w);
    v[4] = f2bf(b.x); v[5] = f2bf(b.y); v[6] = f2bf(b.z); v[7] = f2bf(b.w);
    *(u16x8*)(out + (size_t)i * 8) = v;
}

// scores[row][8] = [s_src h0..3, s_dst h0..3]; one wave per row of h (bf16).
__global__ __launch_bounds__(256)
void score_k(const u16* __restrict__ hs, int ld,
             const float* __restrict__ a_src, const float* __restrict__ a_dst,
             float* __restrict__ scores, int Mrows)
{
    const int wid  = blockIdx.x * 4 + (threadIdx.x >> 6);
    const int lane = threadIdx.x & 63;
    if (wid >= Mrows) return;
    const u16* hp = hs + (size_t)wid * ld + lane * 4;
    u16x4 xv = *(const u16x4*)hp;
    float s1 = 0.f, s2 = 0.f;
#pragma unroll
    for (int k = 0; k < 4; ++k) {
        float x = bf2f(xv[k]);
        s1 = fmaf(x, a_src[lane * 4 + k], s1);
        s2 = fmaf(x, a_dst[lane * 4 + k], s2);
    }
#pragma unroll
    for (int off = 1; off < 16; off <<= 1) {
        s1 += __shfl_xor(s1, off);
        s2 += __shfl_xor(s2, off);
    }
    if ((lane & 15) == 0) {
        scores[(size_t)wid * 8 + (lane >> 4)] = s1;
        scores[(size_t)wid * 8 + 4 + (lane >> 4)] = s2;
    }
}

// One thread per (b,h): full 7x7 leaky-relu + mask + top-3 + softmax.
template<int WRITE_ATTN>
__global__ __launch_bounds__(256)
void alpha_k(const float* __restrict__ scores, const float* __restrict__ em2,
             float* __restrict__ alpha, float* __restrict__ attn_out)
{
    const int t = blockIdx.x * 256 + threadIdx.x;
    const int b = t >> 2;
    const int h = t & 3;

    float ssrc[7], sdst[7];
#pragma unroll
    for (int n = 0; n < 7; ++n) {
        ssrc[n] = scores[(size_t)(b * 7 + n) * 8 + h];
        sdst[n] = scores[(size_t)(b * 7 + n) * 8 + 4 + h];
    }

    float al[49];
#pragma unroll
    for (int i = 0; i < 7; ++i) {
        float e[7];
#pragma unroll
        for (int j = 0; j < 7; ++j) {
            float v = ssrc[i] + sdst[j];
            v = fmaxf(v, 0.2f * v);
            e[j] = fmaf(v, em2[(i * 7 + j) * 2], em2[(i * 7 + j) * 2 + 1]);
        }
        float a1 = -3e38f, b1 = -3e38f, c1 = -3e38f;
#pragma unroll
        for (int j = 0; j < 7; ++j) {
            float v = e[j];
            float t2 = fminf(a1, v); a1 = fmaxf(a1, v);
            float t3 = fminf(b1, t2); b1 = fmaxf(b1, t2);
            c1 = fmaxf(c1, t3);
        }
        float psum = 0.f;
        float p[7];
#pragma unroll
        for (int j = 0; j < 7; ++j) {
            float qv = (e[j] >= c1) ? __expf(e[j] - a1) : 0.f;
            p[j] = qv; psum += qv;
        }
        float inv = 1.f / psum;
#pragma unroll
        for (int j = 0; j < 7; ++j) al[i * 7 + j] = p[j] * inv;
    }

    float* ap = alpha + (size_t)t * 49;
#pragma unroll
    for (int j = 0; j < 49; ++j) ap[j] = al[j];

    if (WRITE_ATTN) {
#pragma unroll
        for (int j = 0; j < 49; ++j) {
            float m = al[j];
            m += __shfl_xor(m, 1);
            m += __shfl_xor(m, 2);
            if (h == 0) attn_out[(size_t)b * 49 + j] = 0.25f * m;
        }
    }
}

// PV + residual + LN + relu. Vectorized 4-wide (R7: scalar u16 access made this
// instruction-bound at 26% HBM). One WAVE per batch element (4 b/block); lane
// owns 4 contiguous cols (u16x4 8B loads/stores); head h = lane>>4. Alpha rows
// loaded per-i (16 lanes share addr -> broadcast). No persistent x array.
__global__ __launch_bounds__(256)
void gat_apply_k(const u16* __restrict__ hh, int ld_hh,
                 const u16* __restrict__ resid, int ld_res, int res_off,
                 const float* __restrict__ alpha,
                 const float* __restrict__ ln_w, const float* __restrict__ ln_b,
                 u16* __restrict__ outp, int out_bs)
{
    const int t = threadIdx.x;
    const int b = blockIdx.x * 4 + (t >> 6);
    const int l = t & 63;
    const int c = l * 4;
    const int h = l >> 4;
    const size_t rowbase = (size_t)b * 7;

    float hv[7][4];
#pragma unroll
    for (int n = 0; n < 7; ++n) {
        u16x4 qv = *(const u16x4*)&hh[(rowbase + n) * ld_hh + c];
#pragma unroll
        for (int k = 0; k < 4; ++k) hv[n][k] = bf2f(qv[k]);
    }

    const float* ap = alpha + ((size_t)b * 4 + h) * 49;
    float4 lw = *(const float4*)&ln_w[c];
    float4 lb = *(const float4*)&ln_b[c];

#pragma unroll
    for (int i = 0; i < 7; ++i) {
        float a0 = ap[i * 7 + 0], a1 = ap[i * 7 + 1], a2 = ap[i * 7 + 2],
              a3 = ap[i * 7 + 3], a4 = ap[i * 7 + 4], a5 = ap[i * 7 + 5],
              a6 = ap[i * 7 + 6];
        u16x4 rr = *(const u16x4*)&resid[(rowbase + i) * ld_res + res_off + c];
        float x[4];
#pragma unroll
        for (int k = 0; k < 4; ++k) {
            float pv = a0 * hv[0][k];
            pv = fmaf(a1, hv[1][k], pv);
            pv = fmaf(a2, hv[2][k], pv);
            pv = fmaf(a3, hv[3][k], pv);
            pv = fmaf(a4, hv[4][k], pv);
            pv = fmaf(a5, hv[5][k], pv);
            pv = fmaf(a6, hv[6][k], pv);
            x[k] = pv + bf2f(rr[k]);
        }
        float s1 = (x[0] + x[1]) + (x[2] + x[3]);
        float s2 = fmaf(x[0], x[0], x[1] * x[1]) + fmaf(x[2], x[2], x[3] * x[3]);
#pragma unroll
        for (int off = 32; off > 0; off >>= 1) {
            s1 += __shfl_xor(s1, off);
            s2 += __shfl_xor(s2, off);
        }
        float mu  = s1 * (1.f / 256.f);
        float var = fmaxf(s2 * (1.f / 256.f) - mu * mu, 0.f);
        float inv = rsqrtf(var + 1e-5f);
        u16x4 o;
        o[0] = f2bf(fmaxf((x[0] - mu) * inv * lw.x + lb.x, 0.f));
        o[1] = f2bf(fmaxf((x[1] - mu) * inv * lw.y + lb.y, 0.f));
        o[2] = f2bf(fmaxf((x[2] - mu) * inv * lw.z + lb.z, 0.f));
        o[3] = f2bf(fmaxf((x[3] - mu) * inv * lw.w + lb.w, 0.f));
        *(u16x4*)&outp[(size_t)b * out_bs + i * 256 + c] = o;
    }
}

// weight transpose/cast + bias fuse + edge_mask. Wt3 padded to 128 rows.
__global__ __launch_bounds__(256)
void prep_k(const float* __restrict__ W1, const float* __restrict__ skip_w, const float* __restrict__ W2,
            const float* __restrict__ base_w1, const float* __restrict__ reg_w1, const float* __restrict__ res_w1,
            const float* __restrict__ skip_b, const float* __restrict__ base_b1, const float* __restrict__ reg_b1,
            const float* __restrict__ res_b1, const float* __restrict__ edge_logits,
            u16* __restrict__ Wt1, u16* __restrict__ Wt2, u16* __restrict__ Wt3,
            float* __restrict__ bias1, float* __restrict__ bias3,
            float* __restrict__ em2, float* __restrict__ em_out)
{
    int idx = blockIdx.x * 256 + threadIdx.x;
    if (idx < 512 * 256) {            // Wt1[n][k] = [W1|skip_w][k][n]
        int n = idx >> 8, k = idx & 255;
        float v = (n < 256) ? W1[k * 256 + n] : skip_w[k * 256 + (n - 256)];
        Wt1[n * 256 + k] = f2bf(v); return;
    }
    idx -= 512 * 256;
    if (idx < 256 * 256) {
        int n = idx >> 8, k = idx & 255;
        Wt2[n * 256 + k] = f2bf(W2[k * 256 + n]); return;
    }
    idx -= 256 * 256;
    if (idx < 128 * 1920) {           // Wt3 rows 80..127 zero
        int n = idx / 1920, k = idx % 1920;
        float v = (n < 32) ? base_w1[k * 32 + n]
                : (n < 64) ? reg_w1[k * 32 + (n - 32)]
                : (n < 80) ? res_w1[k * 16 + (n - 64)] : 0.f;
        Wt3[n * 1920 + k] = f2bf(v); return;
    }
    idx -= 128 * 1920;
    if (idx < 512) { bias1[idx] = (idx < 256) ? 0.f : skip_b[idx - 256]; return; }
    idx -= 512;
    if (idx < 80) {
        bias3[idx] = (idx < 32) ? base_b1[idx] : (idx < 64) ? reg_b1[idx - 32] : res_b1[idx - 64];
        return;
    }
    idx -= 80;
    if (idx < 49) {
        int i = idx / 7, j = idx % 7;
        float s = 1.f / (1.f + __expf(-edge_logits[idx]));
        float m = (i == j) ? 1.f : s;
        em2[idx * 2] = m;
        em2[idx * 2 + 1] = (1.f - m) * (-1e9f);
        em_out[idx] = m;
    }
}

__global__ __launch_bounds__(256)
void ctx_k(const float* __restrict__ ctx, u16* __restrict__ comb)
{
    int idx = blockIdx.x * 256 + threadIdx.x;   // B*128
    int b = idx >> 7, cc = idx & 127;
    comb[(size_t)b * 1920 + 1792 + cc] = f2bf(ctx[idx]);
}

__global__ __launch_bounds__(256)
void head_finish(const float* __restrict__ ho, const float* __restrict__ bp, const float* __restrict__ rf,
                 const float* __restrict__ bw2, const float* __restrict__ bb2,
                 const float* __restrict__ rw2, const float* __restrict__ rb2,
                 const float* __restrict__ gw1, const float* __restrict__ gb1,
                 const float* __restrict__ gw2, const float* __restrict__ gb2,
                 const float* __restrict__ resw2, const float* __restrict__ resb2,
                 float* __restrict__ out_pred, float* __restrict__ out_w, float* __restrict__ out_gate, int B)
{
    int b = blockIdx.x * 256 + threadIdx.x;
    if (b >= B) return;
    const float* o = ho + (size_t)b * 80;

    float z0 = bb2[0], z1 = bb2[1];
#pragma unroll 8
    for (int k = 0; k < 32; ++k) { float v = fmaxf(o[k], 0.f); z0 += v * bw2[k * 2]; z1 += v * bw2[k * 2 + 1]; }
    float mz = fmaxf(z0, z1); float e0 = __expf(z0 - mz), e1 = __expf(z1 - mz); float inv = 1.f / (e0 + e1);
    float wb0 = e0 * inv, wb1 = e1 * inv;

    z0 = rb2[0]; z1 = rb2[1];
#pragma unroll 8
    for (int k = 0; k < 32; ++k) { float v = fmaxf(o[32 + k], 0.f); z0 += v * rw2[k * 2]; z1 += v * rw2[k * 2 + 1]; }
    mz = fmaxf(z0, z1); e0 = __expf(z0 - mz); e1 = __expf(z1 - mz); inv = 1.f / (e0 + e1);
    float wr0 = e0 * inv, wr1 = e1 * inv;

    float g = gb2[0];
#pragma unroll
    for (int j = 0; j < 8; ++j) {
        float a = gb1[j];
#pragma unroll
        for (int i = 0; i < 3; ++i) a += rf[(size_t)b * 3 + i] * gw1[i * 8 + j];
        g += fast_tanh(a) * gw2[j];
    }
    float gg = 1.f / (1.f + __expf(-g));
    float w0 = (1.f - gg) * wb0 + gg * wr0;
    float w1 = (1.f - gg) * wb1 + gg * wr1;
    float pred = w0 * bp[(size_t)b * 2] + w1 * bp[(size_t)b * 2 + 1];
    float r = resb2[0];
#pragma unroll 8
    for (int k = 0; k < 16; ++k) r += fast_tanh(o[64 + k]) * resw2[k];
    pred = fmaxf(pred + r * 0.05f, 0.05f);
    out_pred[b] = pred;
    out_w[(size_t)b * 2] = w0; out_w[(size_t)b * 2 + 1] = w1;
    out_gate[b] = gg;
}

extern "C" void kernel_launch(void* const* d_in, const int* in_sizes, int n_in,
                              void* d_out, int out_size, void* d_ws, size_t ws_size,
                              hipStream_t stream)
{
    const int B = in_sizes[1] / 128;     // context is (B,128)
    const int Mbig = B * 7;

    const float* node_feats   = (const float*)d_in[0];
    const float* context      = (const float*)d_in[1];
    const float* base_preds   = (const float*)d_in[2];
    const float* regime_feats = (const float*)d_in[3];
    const float* edge_logits  = (const float*)d_in[4];
    const float* W1      = (const float*)d_in[5];
    const float* a_src1  = (const float*)d_in[6];
    const float* a_dst1  = (const float*)d_in[7];
    const float* W2      = (const float*)d_in[8];
    const float* a_src2  = (const float*)d_in[9];
    const float* a_dst2  = (const float*)d_in[10];
    const float* ln1_w   = (const float*)d_in[11];
    const float* ln1_b   = (const float*)d_in[12];
    const float* ln2_w   = (const float*)d_in[13];
    const float* ln2_b   = (const float*)d_in[14];
    const float* skip_w  = (const float*)d_in[15];
    const float* skip_b  = (const float*)d_in[16];
    const float* base_w1 = (const float*)d_in[17];
    const float* base_b1 = (const float*)d_in[18];
    const float* base_w2 = (const float*)d_in[19];
    const float* base_b2 = (const float*)d_in[20];
    const float* reg_w1  = (const float*)d_in[21];
    const float* reg_b1  = (const float*)d_in[22];
    const float* reg_w2  = (const float*)d_in[23];
    const float* reg_b2  = (const float*)d_in[24];
    const float* gate_w1 = (const float*)d_in[25];
    const float* gate_b1 = (const float*)d_in[26];
    const float* gate_w2 = (const float*)d_in[27];
    const float* gate_b2 = (const float*)d_in[28];
    const float* res_w1  = (const float*)d_in[29];
    const float* res_b1  = (const float*)d_in[30];
    const float* res_w2  = (const float*)d_in[31];
    const float* res_b2  = (const float*)d_in[32];

    // workspace layout (bytes)
    char* ws = (char*)d_ws;
    size_t off = 0;
    u16* hs1 = (u16*)(ws + off);                       // [h1_pre|skip] Mbig x 512 bf16
    u16* hh2 = (u16*)(ws + off);                       // reuse after GAT1: Mbig x 256 bf16
    off += (size_t)Mbig * 512 * 2;
    u16* hbuf = (u16*)(ws + off);  off += (size_t)Mbig * 256 * 2;   // h: Mbig x 256 bf16
    u16* comb = (u16*)(ws + off);  off += (size_t)B * 1920 * 2;     // combined: B x 1920 bf16
    u16* nf_bf = comb;             // A1 bf16 aliases comb (dead until step 9)
    float* headout = (float*)(ws + off); off += (size_t)B * 80 * 4; // B x 80 f32
    u16* Wt1 = (u16*)(ws + off); off += 512 * 256 * 2;
    u16* Wt2 = (u16*)(ws + off); off += 256 * 256 * 2;
    u16* Wt3 = (u16*)(ws + off); off += (size_t)128 * 1920 * 2;     // padded to 128 rows
    float* bias1 = (float*)(ws + off); off += 512 * 4;
    float* bias3 = (float*)(ws + off); off += 128 * 4;
    float* em2   = (float*)(ws + off); off += 128 * 4;
    float* scoresb = (float*)(ws + off); off += (size_t)Mbig * 8 * 4;   // row scores f32
    float* alphab  = (float*)(ws + off); off += (size_t)B * 4 * 49 * 4; // alpha f32

    float* out_pred = (float*)d_out;
    float* out_w    = out_pred + B;
    float* out_gate = out_pred + 3 * (size_t)B;
    float* out_em   = out_pred + 4 * (size_t)B;
    float* out_attn = out_pred + 4 * (size_t)B + 49;

    const int B4blocks = (B * 4) / 256;

    // 0. node_feats f32 -> bf16 (HBM-bound streaming pass)
    {
        int n8 = Mbig * 256 / 8;
        precast_k<<<dim3((n8 + 255) / 256), dim3(256), 0, stream>>>(node_feats, nf_bf, n8);
    }

    // 1. weight prep + edge mask
    prep_k<<<dim3(1731), dim3(256), 0, stream>>>(W1, skip_w, W2, base_w1, reg_w1, res_w1,
        skip_b, base_b1, reg_b1, res_b1, edge_logits, Wt1, Wt2, Wt3, bias1, bias3, em2, out_em);

    // 2. GEMM1: nf_bf @ [W1|skip_w] -> hs1 (bf16), bias=[0|skip_b]
    gemm_k<1, 0, 0><<<dim3((Mbig / 128) * 4, 1), dim3(256), 0, stream>>>(
        nf_bf, Wt1, bias1, (void*)hs1, Mbig, 512, 256, 256, 512, 4, 256);

    // 3. scores from h1 (= hs1 cols 0..255)
    score_k<<<dim3(Mbig / 4), dim3(256), 0, stream>>>(hs1, 512, a_src1, a_dst1, scoresb, Mbig);

    // 4. alpha for GAT1
    alpha_k<0><<<dim3(B4blocks), dim3(256), 0, stream>>>(scoresb, em2, alphab, (float*)nullptr);

    // 5. GAT1 apply: PV + skip-resid + LN1 + relu -> hbuf
    gat_apply_k<<<dim3(B / 4), dim3(256), 0, stream>>>(
        hs1, 512, hs1, 512, 256, alphab, ln1_w, ln1_b, hbuf, 1792);

    // 6. GEMM2: h @ W2 -> hh2 (reuses hs1 region)
    gemm_k<0, 0, 0><<<dim3((Mbig / 128) * 2, 1), dim3(256), 0, stream>>>(
        hbuf, Wt2, (const float*)nullptr, (void*)hh2, Mbig, 256, 256, 256, 256, 2, 256);

    // 7. scores from h2
    score_k<<<dim3(Mbig / 4), dim3(256), 0, stream>>>(hh2, 256, a_src2, a_dst2, scoresb, Mbig);

    // 8. alpha for GAT2 (+ attn mean output)
    alpha_k<1><<<dim3(B4blocks), dim3(256), 0, stream>>>(scoresb, em2, alphab, out_attn);

    // 9. GAT2 apply: PV + h-resid + LN2 + relu -> comb[:, :1792]
    gat_apply_k<<<dim3(B / 4), dim3(256), 0, stream>>>(
        hh2, 256, hbuf, 256, 0, alphab, ln2_w, ln2_b, comb, 1920);

    // 10. context -> comb[:, 1792:]
    ctx_k<<<dim3(B * 128 / 256), dim3(256), 0, stream>>>(context, comb);

    // 11. GEMM3: comb @ padded-Wt3 + bias -> headout (f32), split-K x2
    hipMemsetAsync(headout, 0, (size_t)B * 80 * 4, stream);
    gemm_k<1, 2, 1><<<dim3(B / 128, 2), dim3(256), 0, stream>>>(
        comb, Wt3, bias3, (void*)headout, B, 80, 1920, 1920, 80, 1, 960);

    // 12. heads -> pred, weights, gate
    head_finish<<<dim3((B + 255) / 256), dim3(256), 0, stream>>>(
        headout, base_preds, regime_feats, base_w2, base_b2, reg_w2, reg_b2,
        gate_w1, gate_b1, gate_w2, gate_b2, res_w2, res_b2, out_pred, out_w, out_gate, B);
}